// Round 4
// baseline (359.096 us; speedup 1.0000x reference)
//
#include <hip/hip_runtime.h>

typedef unsigned short u16;
typedef __attribute__((ext_vector_type(8))) short s16x8;
typedef __attribute__((ext_vector_type(4))) float f32x4;
typedef __attribute__((ext_vector_type(16))) float f32x16;
typedef __attribute__((ext_vector_type(4))) unsigned short u16x4;
typedef __attribute__((ext_vector_type(4))) unsigned int u32x4;

#define MFMA16(a, b, c) __builtin_amdgcn_mfma_f32_16x16x32_bf16(a, b, c, 0, 0, 0)
#define MFMA32(a, b, c) __builtin_amdgcn_mfma_f32_32x32x16_bf16(a, b, c, 0, 0, 0)

__device__ __forceinline__ u16 f2bf(float f) {
  unsigned u = __builtin_bit_cast(unsigned, f);
  u += 0x7fffu + ((u >> 16) & 1u);  // RNE
  return (u16)(u >> 16);
}

__device__ __forceinline__ void async16(const void* g, void* l) {
  __builtin_amdgcn_global_load_lds(
      (const __attribute__((address_space(1))) void*)g,
      (__attribute__((address_space(3))) void*)l, 16, 0, 0);
}

__device__ __forceinline__ s16x8 ld8(const u16* p) { return *(const s16x8*)p; }

// packed f32x2 -> bf16x2 (RNE); no builtin on gfx950, inline asm per T12
__device__ __forceinline__ unsigned cvtpk(float lo, float hi) {
  unsigned r;
  asm("v_cvt_pk_bf16_f32 %0, %1, %2" : "=v"(r) : "v"(lo), "v"(hi));
  return r;
}

// log2(e) / sqrt(64) folded into Q at projection time
#define PRE 0.18033688011112042f

// ---------------- fused fp32 -> bf16 cast of all 5 tensors ----------------
__global__ __launch_bounds__(256) void cvt_all(
    const float* __restrict__ X, const float* __restrict__ Wq,
    const float* __restrict__ Wk, const float* __restrict__ Wv,
    const float* __restrict__ Wo, u16* __restrict__ out) {
  long e = (long)(blockIdx.x * 256 + threadIdx.x) * 4;
  const float* src;
  if (e < 8388608L) src = X + e;
  else if (e < 12582912L) src = Wq + (e - 8388608L);
  else if (e < 13631488L) src = Wk + (e - 12582912L);
  else if (e < 14680064L) src = Wv + (e - 13631488L);
  else src = Wo + (e - 14680064L);
  float4 v = *(const float4*)src;
  u16x4 o = {f2bf(v.x), f2bf(v.y), f2bf(v.z), f2bf(v.w)};
  *(u16x4*)(out + e) = o;
}

// ---------------- NT GEMM: C[m,n] = sum_k A[m,k]*B[n,k] ----------------
// 128x128 tile, BK=32, double-buffered LDS, ONE barrier per K-iter (prefetch
// issued right after the barrier -> a full compute phase to land before the
// next barrier's vmcnt drain). Tiles stored as 64 double-rows x 8 XOR-swizzled
// 16B chunks (conflict-free family).  [round-1 verified @78.5us QKV, 656 TF;
// counted-vmcnt grafts on this 2-barrier structure measured null (m131, r3)]
enum { EPI_QKV = 0, EPI_OUT = 1 };

template <int EPI>
__global__ __launch_bounds__(256) void gemm_nt(
    const u16* __restrict__ A, const u16* __restrict__ Bm,
    const float* __restrict__ cosp, const float* __restrict__ sinp,
    u16* __restrict__ Qo, u16* __restrict__ Ko, u16* __restrict__ Vo,
    float* __restrict__ Co, int K) {
  // [2 buffers][A: 4096 u16 | B: 4096 u16] = 32 KB; epilogue reuses all 32 KB
  __shared__ u16 SM[16384];
  const int t = threadIdx.x;
  const int lane = t & 63;
  const int w = t >> 6, wm = w >> 1, wn = w & 1;
  const int quad = lane >> 4, c16 = lane & 15;
  const int m0 = blockIdx.y * 128, n0 = blockIdx.x * 128;

  f32x4 acc[4][4];
  const f32x4 zero = {0.f, 0.f, 0.f, 0.f};
#pragma unroll
  for (int i = 0; i < 4; ++i)
#pragma unroll
    for (int j = 0; j < 4; ++j) acc[i][j] = zero;

  // staging: chunk c (16B) of a 128x32 tile holds global
  //   double-row dr=c>>3, k8=(c&7)^(dr&7) -> (row 2dr+(k8>>2), colchunk k8&3)
  const u16* gA[2];
  const u16* gB[2];
  int lof[2];
#pragma unroll
  for (int p = 0; p < 2; ++p) {
    int c = t + p * 256;
    int dr = c >> 3, k8 = (c & 7) ^ (dr & 7);
    int row = 2 * dr + (k8 >> 2), col = (k8 & 3) * 8;
    gA[p] = A + (size_t)(m0 + row) * K + col;
    gB[p] = Bm + (size_t)(n0 + row) * K + col;
    lof[p] = c * 8;  // u16 index within a buffer half
  }

  // fragment LDS offsets (loop-invariant; toggle buffer by +8192)
  int aoff[4], boff[4];
#pragma unroll
  for (int i = 0; i < 4; ++i) {
    int rowA = wm * 64 + i * 16 + c16;
    int drA = rowA >> 1;
    int chA = (((rowA & 1) << 2) | quad) ^ (drA & 7);
    aoff[i] = drA * 64 + chA * 8;
    int rowB = wn * 64 + i * 16 + c16;
    int drB = rowB >> 1;
    int chB = (((rowB & 1) << 2) | quad) ^ (drB & 7);
    boff[i] = 4096 + drB * 64 + chB * 8;
  }

  // prologue: stage buffer 0 with k-slab 0
#pragma unroll
  for (int p = 0; p < 2; ++p) {
    async16(gA[p], &SM[lof[p]]);
    async16(gB[p], &SM[4096 + lof[p]]);
  }

  const int niter = K >> 5;
  for (int kt = 0; kt < niter; ++kt) {
    const int cb = (kt & 1) * 8192;
    __syncthreads();  // drains vmcnt: buf[cur] staged; prev reads of buf[nxt] done
    if (kt + 1 < niter) {
      const int nb = 8192 - cb;
#pragma unroll
      for (int p = 0; p < 2; ++p) {
        gA[p] += 32;
        gB[p] += 32;
        async16(gA[p], &SM[nb + lof[p]]);
        async16(gB[p], &SM[nb + 4096 + lof[p]]);
      }
    }
    s16x8 af[4], bfr[4];
#pragma unroll
    for (int i = 0; i < 4; ++i) af[i] = ld8(&SM[cb + aoff[i]]);
#pragma unroll
    for (int j = 0; j < 4; ++j) bfr[j] = ld8(&SM[cb + boff[j]]);
#pragma unroll
    for (int i = 0; i < 4; ++i)
#pragma unroll
      for (int j = 0; j < 4; ++j) acc[i][j] = MFMA16(af[i], bfr[j], acc[i][j]);
  }

  if (EPI == EPI_OUT) {
#pragma unroll
    for (int i = 0; i < 4; ++i)
#pragma unroll
      for (int r = 0; r < 4; ++r) {
        int m = m0 + wm * 64 + i * 16 + quad * 4 + r;
        float* dst = Co + (size_t)m * 2048 + n0 + wn * 64 + c16;
#pragma unroll
        for (int j = 0; j < 4; ++j) dst[j * 16] = acc[i][j][r];
      }
  } else if (n0 >= 2560) {
    // V zone: transpose via LDS -> coalesced 16B stores of V^T [B][8][64][S]
    __syncthreads();  // all K-loop LDS reads done before overwrite
#pragma unroll
    for (int i = 0; i < 4; ++i)
#pragma unroll
      for (int r = 0; r < 4; ++r) {
        int sl = wm * 64 + i * 16 + quad * 4 + r;
#pragma unroll
        for (int j = 0; j < 4; ++j) {
          int dl = wn * 64 + j * 16 + c16;
          SM[dl * 128 + (((sl >> 3) ^ (dl & 15)) * 8) + (sl & 7)] =
              f2bf(acc[i][j][r]);
        }
      }
    __syncthreads();
    int bb = m0 >> 11, m0s = m0 & 2047;
#pragma unroll
    for (int p = 0; p < 8; ++p) {
      int q = p * 256 + t;
      int dl = q >> 4, k = q & 15;
      s16x8 vrow = ld8(&SM[dl * 128 + ((k ^ (dl & 15)) * 8)]);
      int nab = n0 + dl;
      int kvh = (nab - 2560) >> 6, dh = nab & 63;
      *(s16x8*)(Vo + ((size_t)(bb * 8 + kvh) * 64 + dh) * 2048 + m0s + k * 8) =
          vrow;
    }
  } else {
    const int nbase = n0 + wn * 64;
#pragma unroll
    for (int i = 0; i < 4; ++i)
#pragma unroll
      for (int r = 0; r < 4; ++r) {
        int m = m0 + wm * 64 + i * 16 + quad * 4 + r;
        int b = m >> 11, s = m & 2047;
        if (nbase < 2048) {  // Q zone: rope + prescale, store [B][32][S][64]
          int h = nbase >> 6;
          size_t base = ((size_t)(b * 32 + h) * 2048 + s) * 64;
#pragma unroll
          for (int j = 0; j < 2; ++j) {
            int d = j * 16 + c16;
            float v1 = acc[i][j][r], v2 = acc[i][j + 2][r];
            float c1 = cosp[m * 64 + d], s1 = sinp[m * 64 + d];
            float c2 = cosp[m * 64 + d + 32], s2 = sinp[m * 64 + d + 32];
            Qo[base + d] = f2bf((v1 * c1 - v2 * s1) * PRE);
            Qo[base + d + 32] = f2bf((v2 * c2 + v1 * s2) * PRE);
          }
        } else {  // K zone: rope, store [B][8][S][64]
          int h = (nbase - 2048) >> 6;
          size_t base = ((size_t)(b * 8 + h) * 2048 + s) * 64;
#pragma unroll
          for (int j = 0; j < 2; ++j) {
            int d = j * 16 + c16;
            float v1 = acc[i][j][r], v2 = acc[i][j + 2][r];
            float c1 = cosp[m * 64 + d], s1 = sinp[m * 64 + d];
            float c2 = cosp[m * 64 + d + 32], s2 = sinp[m * 64 + d + 32];
            Ko[base + d] = f2bf(v1 * c1 - v2 * s1);
            Ko[base + d + 32] = f2bf(v2 * c2 + v1 * s2);
          }
        }
      }
  }
}

// ---------------- flash attention (causal, GQA) ----------------
// Round-4: grid (16 q-tiles, 64 b*h) = 1024 blocks -> 4 blocks/CU (was 512 =
// 2/CU, OccupancyPercent 19%): the schedule is latency/barrier-bound with all
// pipes <60%, so doubling resident waves is the lever. Heavy tiles dispatch
// first (qt = 15 - blockIdx.x). T5 s_setprio(1) around QK and PV MFMA
// clusters (independent blocks -> m191's attn-positive regime, +4-7%).
// BQ=128 (4 waves x 32 rows), BKV=64. Double-buffered K/V, ONE barrier/iter.
// Swapped-operand 32x32x16 MFMA (S^T = mfma(K,Q)) + fully in-register P via
// T12 (16 v_cvt_pk_bf16_f32 + 8 permlane32_swap per iter). Fixed-m (m=0)
// online softmax; l-reduction deferred to epilogue.  [core verified round 1]
__global__ __launch_bounds__(256) void attn(const u16* __restrict__ Q,
                                            const u16* __restrict__ Kg,
                                            const u16* __restrict__ Vg,
                                            u16* __restrict__ O) {
  __shared__ u16 Ks[2][4096];   // [buf][64 keys][64 d], XOR-swizzled chunks
  __shared__ u16 Vs[2][4096];   // [buf][64 d][64 keys] (V^T), same swizzle
  __shared__ float Lred[128];   // per-wave 1/l broadcast (32 floats/wave)
  const int t = threadIdx.x;
  const int lane = t & 63;
  const int w = t >> 6;
  const int l31 = lane & 31, hi = lane >> 5;
  const int bh = blockIdx.y;
  const int b = bh >> 5, h = bh & 31;
  const int kvh = h >> 2;  // G = 4

  const u16* Qbase = Q + ((size_t)(b * 32 + h) * 2048) * 64;
  const u16* Kbase = Kg + ((size_t)(b * 8 + kvh) * 2048) * 64;
  const u16* Vbase = Vg + ((size_t)(b * 8 + kvh) * 64) * 2048;

  const int sr0 = t >> 3, sc0 = ((t & 7) ^ (sr0 & 7)) * 8;
  const int sr1 = (t + 256) >> 3, sc1 = (((t + 256) & 7) ^ (sr1 & 7)) * 8;

  int off8[4];
#pragma unroll
  for (int c = 0; c < 4; ++c) off8[c] = ((2 * c + hi) ^ (l31 & 7)) * 8;
  const int rbB = l31 * 64;

  const int qt = 15 - blockIdx.x;  // heavy tiles first
  const int q0 = qt * 128;
  const int rbase = q0 + w * 32;
  const int qrow = rbase + l31;  // this lane's q-row (S^T column)

  s16x8 qf[4];
#pragma unroll
  for (int dc = 0; dc < 4; ++dc)
    qf[dc] = ld8(Qbase + (size_t)qrow * 64 + dc * 16 + hi * 8);

  f32x16 oacc[2];
#pragma unroll
  for (int dn = 0; dn < 2; ++dn)
#pragma unroll
    for (int r = 0; r < 16; ++r) oacc[dn][r] = 0.f;
  float lacc = 0.f;

  const int nkt = 2 * qt + 2;

  {
    async16(Kbase + sr0 * 64 + sc0, &Ks[0][t * 8]);
    async16(Kbase + sr1 * 64 + sc1, &Ks[0][t * 8 + 2048]);
    async16(Vbase + (size_t)sr0 * 2048 + sc0, &Vs[0][t * 8]);
    async16(Vbase + (size_t)sr1 * 2048 + sc1, &Vs[0][t * 8 + 2048]);
  }

  for (int kt = 0; kt < nkt; ++kt) {
    const int cur = kt & 1;
    __syncthreads();  // buf[cur] staged; prev reads of buf[1-cur] done
    if (kt + 1 < nkt) {
      const int nxt = 1 - cur;
      const u16* kg = Kbase + (kt + 1) * 4096;
      async16(kg + sr0 * 64 + sc0, &Ks[nxt][t * 8]);
      async16(kg + sr1 * 64 + sc1, &Ks[nxt][t * 8 + 2048]);
      async16(Vbase + (size_t)sr0 * 2048 + (kt + 1) * 64 + sc0,
              &Vs[nxt][t * 8]);
      async16(Vbase + (size_t)sr1 * 2048 + (kt + 1) * 64 + sc1,
              &Vs[nxt][t * 8 + 2048]);
    }
    const u16* Kb = Ks[cur];
    const u16* Vb = Vs[cur];

#pragma unroll
    for (int kn = 0; kn < 2; ++kn) {
      const int kb0 = kt * 64 + kn * 32;
      if (kb0 <= rbase + 31) {  // skip fully-masked 32-key tiles
        f32x16 s_;
#pragma unroll
        for (int r = 0; r < 16; ++r) s_[r] = 0.f;
        __builtin_amdgcn_s_setprio(1);
#pragma unroll
        for (int dc = 0; dc < 4; ++dc) {
          s16x8 kf = ld8(&Kb[kn * 2048 + rbB + off8[dc]]);
          s_ = MFMA32(kf, qf[dc], s_);
        }
        __builtin_amdgcn_s_setprio(0);
        if (kb0 + 31 > rbase) {  // causal mask on diagonal tiles
          const int kb = kb0 + 4 * hi;
#pragma unroll
          for (int r = 0; r < 16; ++r)
            if (kb + (r & 3) + 8 * (r >> 2) > qrow) s_[r] = -1e30f;
        }
        float p[16];
#pragma unroll
        for (int r = 0; r < 16; ++r) p[r] = __builtin_amdgcn_exp2f(s_[r]);
        {
          float e0 = p[0] + p[1], e1 = p[2] + p[3], e2 = p[4] + p[5],
                e3 = p[6] + p[7], e4 = p[8] + p[9], e5 = p[10] + p[11],
                e6 = p[12] + p[13], e7 = p[14] + p[15];
          lacc += ((e0 + e1) + (e2 + e3)) + ((e4 + e5) + (e6 + e7));
        }
#pragma unroll
        for (int c2 = 0; c2 < 2; ++c2) {
          unsigned a0 = cvtpk(p[8 * c2 + 0], p[8 * c2 + 1]);
          unsigned b0 = cvtpk(p[8 * c2 + 4], p[8 * c2 + 5]);
          unsigned a1 = cvtpk(p[8 * c2 + 2], p[8 * c2 + 3]);
          unsigned b1 = cvtpk(p[8 * c2 + 6], p[8 * c2 + 7]);
          auto s0 = __builtin_amdgcn_permlane32_swap(a0, b0, false, false);
          auto s1 = __builtin_amdgcn_permlane32_swap(a1, b1, false, false);
          u32x4 fw = {(unsigned)s0[0], (unsigned)s1[0], (unsigned)s0[1],
                      (unsigned)s1[1]};
          s16x8 F = __builtin_bit_cast(s16x8, fw);
          const int kk = 2 * kn + c2;
          __builtin_amdgcn_s_setprio(1);
#pragma unroll
          for (int dn = 0; dn < 2; ++dn) {
            s16x8 vf = ld8(&Vb[dn * 2048 + rbB + off8[kk]]);
            oacc[dn] = MFMA32(F, vf, oacc[dn]);
          }
          __builtin_amdgcn_s_setprio(0);
        }
      }
    }
  }

  {
    float ltot = lacc + __shfl_xor(lacc, 32);
    if (lane < 32) Lred[w * 32 + l31] = 1.f / ltot;
    f32x4 lv[4];
#pragma unroll
    for (int g = 0; g < 4; ++g)
      lv[g] = *(const f32x4*)&Lred[w * 32 + 8 * g + 4 * hi];
#pragma unroll
    for (int dn = 0; dn < 2; ++dn)
#pragma unroll
      for (int g = 0; g < 4; ++g)
#pragma unroll
        for (int j = 0; j < 4; ++j) {
          int s = rbase + 8 * g + 4 * hi + j;
          O[((size_t)(b * 2048 + s)) * 2048 + h * 64 + dn * 32 + l31] =
              f2bf(oacc[dn][4 * g + j] * lv[g][j]);
        }
  }
}

// ---------------- launch ----------------
extern "C" void kernel_launch(void* const* d_in, const int* in_sizes, int n_in,
                              void* d_out, int out_size, void* d_ws,
                              size_t ws_size, hipStream_t stream) {
  const float* X = (const float*)d_in[0];
  const float* cosp = (const float*)d_in[1];
  const float* sinp = (const float*)d_in[2];
  const float* Wq = (const float*)d_in[4];
  const float* Wk = (const float*)d_in[5];
  const float* Wv = (const float*)d_in[6];
  const float* Wo = (const float*)d_in[7];
  float* out = (float*)d_out;

  u16* Xb = (u16*)d_ws;       // 8,388,608
  u16* Wqkv = Xb + 8388608;   // 3072x2048 (Wq|Wk|Wv rows)
  u16* Wob = Wqkv + 6291456;  // 4,194,304
  u16* Qr = Wob + 4194304;    // [2][32][2048][64]  (pre-scaled)
  u16* Kr = Qr + 8388608;     // [2][8][2048][64]
  u16* Vt = Kr + 2097152;     // [2][8][64][2048]
  u16* Ob = Vt + 2097152;     // [2][2048][2048]

  cvt_all<<<18432, 256, 0, stream>>>(X, Wq, Wk, Wv, Wo, Xb);

  gemm_nt<EPI_QKV><<<dim3(24, 32), 256, 0, stream>>>(
      Xb, Wqkv, cosp, sinp, Qr, Kr, Vt, nullptr, 2048);

  attn<<<dim3(16, 64), 256, 0, stream>>>(Qr, Kr, Vt, Ob);

  gemm_nt<EPI_OUT><<<dim3(16, 32), 256, 0, stream>>>(
      Ob, Wob, nullptr, nullptr, nullptr, nullptr, nullptr, out, 2048);
}

// Round 5
// 326.523 us; speedup vs baseline: 1.0998x; 1.0998x over previous
//
#include <hip/hip_runtime.h>

typedef unsigned short u16;
typedef __attribute__((ext_vector_type(8))) short s16x8;
typedef __attribute__((ext_vector_type(4))) float f32x4;
typedef __attribute__((ext_vector_type(16))) float f32x16;
typedef __attribute__((ext_vector_type(4))) unsigned short u16x4;
typedef __attribute__((ext_vector_type(4))) unsigned int u32x4;

#define MFMA16(a, b, c) __builtin_amdgcn_mfma_f32_16x16x32_bf16(a, b, c, 0, 0, 0)
#define MFMA32(a, b, c) __builtin_amdgcn_mfma_f32_32x32x16_bf16(a, b, c, 0, 0, 0)

__device__ __forceinline__ u16 f2bf(float f) {
  unsigned u = __builtin_bit_cast(unsigned, f);
  u += 0x7fffu + ((u >> 16) & 1u);  // RNE
  return (u16)(u >> 16);
}

__device__ __forceinline__ void async16(const void* g, void* l) {
  __builtin_amdgcn_global_load_lds(
      (const __attribute__((address_space(1))) void*)g,
      (__attribute__((address_space(3))) void*)l, 16, 0, 0);
}

__device__ __forceinline__ s16x8 ld8(const u16* p) { return *(const s16x8*)p; }

// packed f32x2 -> bf16x2 (RNE); no builtin on gfx950, inline asm per T12
__device__ __forceinline__ unsigned cvtpk(float lo, float hi) {
  unsigned r;
  asm("v_cvt_pk_bf16_f32 %0, %1, %2" : "=v"(r) : "v"(lo), "v"(hi));
  return r;
}

// log2(e) / sqrt(64) folded into Q at projection time
#define PRE 0.18033688011112042f

// ---------------- fused fp32 -> bf16 cast of all 5 tensors ----------------
__global__ __launch_bounds__(256) void cvt_all(
    const float* __restrict__ X, const float* __restrict__ Wq,
    const float* __restrict__ Wk, const float* __restrict__ Wv,
    const float* __restrict__ Wo, u16* __restrict__ out) {
  long e = (long)(blockIdx.x * 256 + threadIdx.x) * 4;
  const float* src;
  if (e < 8388608L) src = X + e;
  else if (e < 12582912L) src = Wq + (e - 8388608L);
  else if (e < 13631488L) src = Wk + (e - 12582912L);
  else if (e < 14680064L) src = Wv + (e - 13631488L);
  else src = Wo + (e - 14680064L);
  float4 v = *(const float4*)src;
  u16x4 o = {f2bf(v.x), f2bf(v.y), f2bf(v.z), f2bf(v.w)};
  *(u16x4*)(out + e) = o;
}

// ---------------- NT GEMM: C[m,n] = sum_k A[m,k]*B[n,k] ----------------
// 128x128 tile, BK=32, double-buffered LDS, ONE barrier per K-iter (prefetch
// issued right after the barrier -> a full compute phase to land before the
// next barrier's vmcnt drain). Tiles stored as 64 double-rows x 8 XOR-swizzled
// 16B chunks (conflict-free family).  [round-1 verified @78.5us QKV, 656 TF;
// counted-vmcnt grafts on this 2-barrier structure measured null (m131, r3);
// 256^2-tile variants underfill the 256-CU grid and lose (r3)]
enum { EPI_QKV = 0, EPI_OUT = 1 };

template <int EPI>
__global__ __launch_bounds__(256) void gemm_nt(
    const u16* __restrict__ A, const u16* __restrict__ Bm,
    const float* __restrict__ cosp, const float* __restrict__ sinp,
    u16* __restrict__ Qo, u16* __restrict__ Ko, u16* __restrict__ Vo,
    float* __restrict__ Co, int K) {
  // [2 buffers][A: 4096 u16 | B: 4096 u16] = 32 KB; epilogue reuses all 32 KB
  __shared__ u16 SM[16384];
  const int t = threadIdx.x;
  const int lane = t & 63;
  const int w = t >> 6, wm = w >> 1, wn = w & 1;
  const int quad = lane >> 4, c16 = lane & 15;
  const int m0 = blockIdx.y * 128, n0 = blockIdx.x * 128;

  f32x4 acc[4][4];
  const f32x4 zero = {0.f, 0.f, 0.f, 0.f};
#pragma unroll
  for (int i = 0; i < 4; ++i)
#pragma unroll
    for (int j = 0; j < 4; ++j) acc[i][j] = zero;

  // staging: chunk c (16B) of a 128x32 tile holds global
  //   double-row dr=c>>3, k8=(c&7)^(dr&7) -> (row 2dr+(k8>>2), colchunk k8&3)
  const u16* gA[2];
  const u16* gB[2];
  int lof[2];
#pragma unroll
  for (int p = 0; p < 2; ++p) {
    int c = t + p * 256;
    int dr = c >> 3, k8 = (c & 7) ^ (dr & 7);
    int row = 2 * dr + (k8 >> 2), col = (k8 & 3) * 8;
    gA[p] = A + (size_t)(m0 + row) * K + col;
    gB[p] = Bm + (size_t)(n0 + row) * K + col;
    lof[p] = c * 8;  // u16 index within a buffer half
  }

  // fragment LDS offsets (loop-invariant; toggle buffer by +8192)
  int aoff[4], boff[4];
#pragma unroll
  for (int i = 0; i < 4; ++i) {
    int rowA = wm * 64 + i * 16 + c16;
    int drA = rowA >> 1;
    int chA = (((rowA & 1) << 2) | quad) ^ (drA & 7);
    aoff[i] = drA * 64 + chA * 8;
    int rowB = wn * 64 + i * 16 + c16;
    int drB = rowB >> 1;
    int chB = (((rowB & 1) << 2) | quad) ^ (drB & 7);
    boff[i] = 4096 + drB * 64 + chB * 8;
  }

  // prologue: stage buffer 0 with k-slab 0
#pragma unroll
  for (int p = 0; p < 2; ++p) {
    async16(gA[p], &SM[lof[p]]);
    async16(gB[p], &SM[4096 + lof[p]]);
  }

  const int niter = K >> 5;
  for (int kt = 0; kt < niter; ++kt) {
    const int cb = (kt & 1) * 8192;
    __syncthreads();  // drains vmcnt: buf[cur] staged; prev reads of buf[nxt] done
    if (kt + 1 < niter) {
      const int nb = 8192 - cb;
#pragma unroll
      for (int p = 0; p < 2; ++p) {
        gA[p] += 32;
        gB[p] += 32;
        async16(gA[p], &SM[nb + lof[p]]);
        async16(gB[p], &SM[nb + 4096 + lof[p]]);
      }
    }
    s16x8 af[4], bfr[4];
#pragma unroll
    for (int i = 0; i < 4; ++i) af[i] = ld8(&SM[cb + aoff[i]]);
#pragma unroll
    for (int j = 0; j < 4; ++j) bfr[j] = ld8(&SM[cb + boff[j]]);
#pragma unroll
    for (int i = 0; i < 4; ++i)
#pragma unroll
      for (int j = 0; j < 4; ++j) acc[i][j] = MFMA16(af[i], bfr[j], acc[i][j]);
  }

  if (EPI == EPI_OUT) {
#pragma unroll
    for (int i = 0; i < 4; ++i)
#pragma unroll
      for (int r = 0; r < 4; ++r) {
        int m = m0 + wm * 64 + i * 16 + quad * 4 + r;
        float* dst = Co + (size_t)m * 2048 + n0 + wn * 64 + c16;
#pragma unroll
        for (int j = 0; j < 4; ++j) dst[j * 16] = acc[i][j][r];
      }
  } else if (n0 >= 2560) {
    // V zone: transpose via LDS -> coalesced 16B stores of V^T [B][8][64][S]
    __syncthreads();  // all K-loop LDS reads done before overwrite
#pragma unroll
    for (int i = 0; i < 4; ++i)
#pragma unroll
      for (int r = 0; r < 4; ++r) {
        int sl = wm * 64 + i * 16 + quad * 4 + r;
#pragma unroll
        for (int j = 0; j < 4; ++j) {
          int dl = wn * 64 + j * 16 + c16;
          SM[dl * 128 + (((sl >> 3) ^ (dl & 15)) * 8) + (sl & 7)] =
              f2bf(acc[i][j][r]);
        }
      }
    __syncthreads();
    int bb = m0 >> 11, m0s = m0 & 2047;
#pragma unroll
    for (int p = 0; p < 8; ++p) {
      int q = p * 256 + t;
      int dl = q >> 4, k = q & 15;
      s16x8 vrow = ld8(&SM[dl * 128 + ((k ^ (dl & 15)) * 8)]);
      int nab = n0 + dl;
      int kvh = (nab - 2560) >> 6, dh = nab & 63;
      *(s16x8*)(Vo + ((size_t)(bb * 8 + kvh) * 64 + dh) * 2048 + m0s + k * 8) =
          vrow;
    }
  } else {
    const int nbase = n0 + wn * 64;
#pragma unroll
    for (int i = 0; i < 4; ++i)
#pragma unroll
      for (int r = 0; r < 4; ++r) {
        int m = m0 + wm * 64 + i * 16 + quad * 4 + r;
        int b = m >> 11, s = m & 2047;
        if (nbase < 2048) {  // Q zone: rope + prescale, store [B][32][S][64]
          int h = nbase >> 6;
          size_t base = ((size_t)(b * 32 + h) * 2048 + s) * 64;
#pragma unroll
          for (int j = 0; j < 2; ++j) {
            int d = j * 16 + c16;
            float v1 = acc[i][j][r], v2 = acc[i][j + 2][r];
            float c1 = cosp[m * 64 + d], s1 = sinp[m * 64 + d];
            float c2 = cosp[m * 64 + d + 32], s2 = sinp[m * 64 + d + 32];
            Qo[base + d] = f2bf((v1 * c1 - v2 * s1) * PRE);
            Qo[base + d + 32] = f2bf((v2 * c2 + v1 * s2) * PRE);
          }
        } else {  // K zone: rope, store [B][8][S][64]
          int h = (nbase - 2048) >> 6;
          size_t base = ((size_t)(b * 8 + h) * 2048 + s) * 64;
#pragma unroll
          for (int j = 0; j < 2; ++j) {
            int d = j * 16 + c16;
            float v1 = acc[i][j][r], v2 = acc[i][j + 2][r];
            float c1 = cosp[m * 64 + d], s1 = sinp[m * 64 + d];
            float c2 = cosp[m * 64 + d + 32], s2 = sinp[m * 64 + d + 32];
            Ko[base + d] = f2bf(v1 * c1 - v2 * s1);
            Ko[base + d + 32] = f2bf(v2 * c2 + v1 * s2);
          }
        }
      }
  }
}

// ---------------- flash attention (causal, GQA) ----------------
// grid: (8 qt-pairs, 64 b*h). Each block does q-tiles {x, 15-x}: exactly 34
// k-iters -> PERFECT load balance (round-4 un-pairing gave a 17x work spread
// with no backfill slack and regressed 77->122us; pairing restored).
// BQ=128 (4 waves x 32 rows), BKV=64. Double-buffered K/V, ONE barrier/iter.
// Swapped-operand 32x32x16 MFMA (S^T = mfma(K,Q)) + fully in-register P via
// T12 (cvt_pk_bf16 + permlane32_swap). Fixed-m (m=0) online softmax;
// l-reduction deferred to epilogue.
//
// Round-5: batch BOTH kn half-tiles per kt (T15-style dep-break): issue both
// QK MFMA chains (s0,s1 independent), then 32 independent exp2, then both
// fragment builds, then all 8 PV MFMAs (alternating oacc[0]/oacc[1]).
// Counters showed VALUBusy 33% >> MfmaUtil 11% at low occupancy => intra-wave
// serial chain was the bound; this doubles ILP on every link. All indexing
// compile-time-static (rule #20). s_setprio around MFMA clusters (m191).
__global__ __launch_bounds__(256) void attn(const u16* __restrict__ Q,
                                            const u16* __restrict__ Kg,
                                            const u16* __restrict__ Vg,
                                            u16* __restrict__ O) {
  __shared__ u16 Ks[2][4096];   // [buf][64 keys][64 d], XOR-swizzled chunks
  __shared__ u16 Vs[2][4096];   // [buf][64 d][64 keys] (V^T), same swizzle
  __shared__ float Lred[128];   // per-wave 1/l broadcast (32 floats/wave)
  const int t = threadIdx.x;
  const int lane = t & 63;
  const int w = t >> 6;
  const int l31 = lane & 31, hi = lane >> 5;
  const int bh = blockIdx.y;
  const int b = bh >> 5, h = bh & 31;
  const int kvh = h >> 2;  // G = 4

  const u16* Qbase = Q + ((size_t)(b * 32 + h) * 2048) * 64;
  const u16* Kbase = Kg + ((size_t)(b * 8 + kvh) * 2048) * 64;
  const u16* Vbase = Vg + ((size_t)(b * 8 + kvh) * 64) * 2048;

  const int sr0 = t >> 3, sc0 = ((t & 7) ^ (sr0 & 7)) * 8;
  const int sr1 = (t + 256) >> 3, sc1 = (((t + 256) & 7) ^ (sr1 & 7)) * 8;

  int off8[4];
#pragma unroll
  for (int c = 0; c < 4; ++c) off8[c] = ((2 * c + hi) ^ (l31 & 7)) * 8;
  const int rbB = l31 * 64;

  for (int ph = 0; ph < 2; ++ph) {
    const int qt = ph ? 15 - blockIdx.x : blockIdx.x;
    const int q0 = qt * 128;
    const int rbase = q0 + w * 32;
    const int qrow = rbase + l31;  // this lane's q-row (S^T column)

    s16x8 qf[4];
#pragma unroll
    for (int dc = 0; dc < 4; ++dc)
      qf[dc] = ld8(Qbase + (size_t)qrow * 64 + dc * 16 + hi * 8);

    f32x16 oacc[2];
#pragma unroll
    for (int dn = 0; dn < 2; ++dn)
#pragma unroll
      for (int r = 0; r < 16; ++r) oacc[dn][r] = 0.f;
    float lacc = 0.f;

    const int nkt = 2 * qt + 2;

    __syncthreads();  // previous phase's LDS reads done before restaging buf0
    {
      async16(Kbase + sr0 * 64 + sc0, &Ks[0][t * 8]);
      async16(Kbase + sr1 * 64 + sc1, &Ks[0][t * 8 + 2048]);
      async16(Vbase + (size_t)sr0 * 2048 + sc0, &Vs[0][t * 8]);
      async16(Vbase + (size_t)sr1 * 2048 + sc1, &Vs[0][t * 8 + 2048]);
    }

    for (int kt = 0; kt < nkt; ++kt) {
      const int cur = kt & 1;
      __syncthreads();  // buf[cur] staged; prev reads of buf[1-cur] done
      if (kt + 1 < nkt) {
        const int nxt = 1 - cur;
        const u16* kg = Kbase + (kt + 1) * 4096;
        async16(kg + sr0 * 64 + sc0, &Ks[nxt][t * 8]);
        async16(kg + sr1 * 64 + sc1, &Ks[nxt][t * 8 + 2048]);
        async16(Vbase + (size_t)sr0 * 2048 + (kt + 1) * 64 + sc0,
                &Vs[nxt][t * 8]);
        async16(Vbase + (size_t)sr1 * 2048 + (kt + 1) * 64 + sc1,
                &Vs[nxt][t * 8 + 2048]);
      }
      const u16* Kb = Ks[cur];
      const u16* Vb = Vs[cur];

      const int kb0 = kt * 64;
      const bool do0 = (kb0 <= rbase + 31);       // kn=0 half-tile live
      const bool do1 = (kb0 + 32 <= rbase + 31);  // kn=1 half-tile live
      if (do0) {
        // --- both QK^T chains issued back-to-back (independent accs) ---
        f32x16 s0, s1;
#pragma unroll
        for (int r = 0; r < 16; ++r) s0[r] = 0.f;
#pragma unroll
        for (int r = 0; r < 16; ++r) s1[r] = 0.f;
        __builtin_amdgcn_s_setprio(1);
#pragma unroll
        for (int dc = 0; dc < 4; ++dc) {
          s16x8 kf = ld8(&Kb[rbB + off8[dc]]);
          s0 = MFMA32(kf, qf[dc], s0);
        }
        if (do1) {
#pragma unroll
          for (int dc = 0; dc < 4; ++dc) {
            s16x8 kf = ld8(&Kb[2048 + rbB + off8[dc]]);
            s1 = MFMA32(kf, qf[dc], s1);
          }
        }
        __builtin_amdgcn_s_setprio(0);
        // --- causal masks (diagonal tiles only; wave-uniform branches) ---
        if (kb0 + 31 > rbase) {
          const int kb = kb0 + 4 * hi;
#pragma unroll
          for (int r = 0; r < 16; ++r)
            if (kb + (r & 3) + 8 * (r >> 2) > qrow) s0[r] = -1e30f;
        }
        if (do1 && kb0 + 63 > rbase) {
          const int kb = kb0 + 32 + 4 * hi;
#pragma unroll
          for (int r = 0; r < 16; ++r)
            if (kb + (r & 3) + 8 * (r >> 2) > qrow) s1[r] = -1e30f;
        }
        // --- 16/32 independent exp2 ---
        float p0[16], p1[16];
#pragma unroll
        for (int r = 0; r < 16; ++r) p0[r] = __builtin_amdgcn_exp2f(s0[r]);
        if (do1) {
#pragma unroll
          for (int r = 0; r < 16; ++r) p1[r] = __builtin_amdgcn_exp2f(s1[r]);
        }
        // --- l accumulation (balanced trees) ---
        {
          float e0 = p0[0] + p0[1], e1 = p0[2] + p0[3], e2 = p0[4] + p0[5],
                e3 = p0[6] + p0[7], e4 = p0[8] + p0[9], e5 = p0[10] + p0[11],
                e6 = p0[12] + p0[13], e7 = p0[14] + p0[15];
          lacc += ((e0 + e1) + (e2 + e3)) + ((e4 + e5) + (e6 + e7));
        }
        if (do1) {
          float e0 = p1[0] + p1[1], e1 = p1[2] + p1[3], e2 = p1[4] + p1[5],
                e3 = p1[6] + p1[7], e4 = p1[8] + p1[9], e5 = p1[10] + p1[11],
                e6 = p1[12] + p1[13], e7 = p1[14] + p1[15];
          lacc += ((e0 + e1) + (e2 + e3)) + ((e4 + e5) + (e6 + e7));
        }
        // --- T12 fragment builds for all live kk ---
        s16x8 F0, F1, F2, F3;
        {
          unsigned a0 = cvtpk(p0[0], p0[1]), b0 = cvtpk(p0[4], p0[5]);
          unsigned a1 = cvtpk(p0[2], p0[3]), b1 = cvtpk(p0[6], p0[7]);
          auto s0s = __builtin_amdgcn_permlane32_swap(a0, b0, false, false);
          auto s1s = __builtin_amdgcn_permlane32_swap(a1, b1, false, false);
          u32x4 fw = {(unsigned)s0s[0], (unsigned)s1s[0], (unsigned)s0s[1],
                      (unsigned)s1s[1]};
          F0 = __builtin_bit_cast(s16x8, fw);
          unsigned a2 = cvtpk(p0[8], p0[9]), b2 = cvtpk(p0[12], p0[13]);
          unsigned a3 = cvtpk(p0[10], p0[11]), b3 = cvtpk(p0[14], p0[15]);
          auto s2s = __builtin_amdgcn_permlane32_swap(a2, b2, false, false);
          auto s3s = __builtin_amdgcn_permlane32_swap(a3, b3, false, false);
          u32x4 fw2 = {(unsigned)s2s[0], (unsigned)s3s[0], (unsigned)s2s[1],
                       (unsigned)s3s[1]};
          F1 = __builtin_bit_cast(s16x8, fw2);
        }
        if (do1) {
          unsigned a0 = cvtpk(p1[0], p1[1]), b0 = cvtpk(p1[4], p1[5]);
          unsigned a1 = cvtpk(p1[2], p1[3]), b1 = cvtpk(p1[6], p1[7]);
          auto s0s = __builtin_amdgcn_permlane32_swap(a0, b0, false, false);
          auto s1s = __builtin_amdgcn_permlane32_swap(a1, b1, false, false);
          u32x4 fw = {(unsigned)s0s[0], (unsigned)s1s[0], (unsigned)s0s[1],
                      (unsigned)s1s[1]};
          F2 = __builtin_bit_cast(s16x8, fw);
          unsigned a2 = cvtpk(p1[8], p1[9]), b2 = cvtpk(p1[12], p1[13]);
          unsigned a3 = cvtpk(p1[10], p1[11]), b3 = cvtpk(p1[14], p1[15]);
          auto s2s = __builtin_amdgcn_permlane32_swap(a2, b2, false, false);
          auto s3s = __builtin_amdgcn_permlane32_swap(a3, b3, false, false);
          u32x4 fw2 = {(unsigned)s2s[0], (unsigned)s3s[0], (unsigned)s2s[1],
                       (unsigned)s3s[1]};
          F3 = __builtin_bit_cast(s16x8, fw2);
        }
        // --- all PV MFMAs, alternating accumulators (dep distance 2) ---
        __builtin_amdgcn_s_setprio(1);
#pragma unroll
        for (int dn = 0; dn < 2; ++dn) {
          s16x8 vf = ld8(&Vb[dn * 2048 + rbB + off8[0]]);
          oacc[dn] = MFMA32(F0, vf, oacc[dn]);
        }
#pragma unroll
        for (int dn = 0; dn < 2; ++dn) {
          s16x8 vf = ld8(&Vb[dn * 2048 + rbB + off8[1]]);
          oacc[dn] = MFMA32(F1, vf, oacc[dn]);
        }
        if (do1) {
#pragma unroll
          for (int dn = 0; dn < 2; ++dn) {
            s16x8 vf = ld8(&Vb[dn * 2048 + rbB + off8[2]]);
            oacc[dn] = MFMA32(F2, vf, oacc[dn]);
          }
#pragma unroll
          for (int dn = 0; dn < 2; ++dn) {
            s16x8 vf = ld8(&Vb[dn * 2048 + rbB + off8[3]]);
            oacc[dn] = MFMA32(F3, vf, oacc[dn]);
          }
        }
        __builtin_amdgcn_s_setprio(0);
      }
    }

    // epilogue: l split across hi halves -> one shfl_xor(32), broadcast 1/l
    // through wave-private LDS, scale + store O
    {
      float ltot = lacc + __shfl_xor(lacc, 32);
      if (lane < 32) Lred[w * 32 + l31] = 1.f / ltot;
      f32x4 lv[4];
#pragma unroll
      for (int g = 0; g < 4; ++g)
        lv[g] = *(const f32x4*)&Lred[w * 32 + 8 * g + 4 * hi];
#pragma unroll
      for (int dn = 0; dn < 2; ++dn)
#pragma unroll
        for (int g = 0; g < 4; ++g)
#pragma unroll
          for (int j = 0; j < 4; ++j) {
            int s = rbase + 8 * g + 4 * hi + j;
            O[((size_t)(b * 2048 + s)) * 2048 + h * 64 + dn * 32 + l31] =
                f2bf(oacc[dn][4 * g + j] * lv[g][j]);
          }
    }
  }
}

// ---------------- launch ----------------
extern "C" void kernel_launch(void* const* d_in, const int* in_sizes, int n_in,
                              void* d_out, int out_size, void* d_ws,
                              size_t ws_size, hipStream_t stream) {
  const float* X = (const float*)d_in[0];
  const float* cosp = (const float*)d_in[1];
  const float* sinp = (const float*)d_in[2];
  const float* Wq = (const float*)d_in[4];
  const float* Wk = (const float*)d_in[5];
  const float* Wv = (const float*)d_in[6];
  const float* Wo = (const float*)d_in[7];
  float* out = (float*)d_out;

  u16* Xb = (u16*)d_ws;       // 8,388,608
  u16* Wqkv = Xb + 8388608;   // 3072x2048 (Wq|Wk|Wv rows)
  u16* Wob = Wqkv + 6291456;  // 4,194,304
  u16* Qr = Wob + 4194304;    // [2][32][2048][64]  (pre-scaled)
  u16* Kr = Qr + 8388608;     // [2][8][2048][64]
  u16* Vt = Kr + 2097152;     // [2][8][64][2048]
  u16* Ob = Vt + 2097152;     // [2][2048][2048]

  cvt_all<<<18432, 256, 0, stream>>>(X, Wq, Wk, Wv, Wo, Xb);

  gemm_nt<EPI_QKV><<<dim3(24, 32), 256, 0, stream>>>(
      Xb, Wqkv, cosp, sinp, Qr, Kr, Vt, nullptr, 2048);

  attn<<<dim3(8, 64), 256, 0, stream>>>(Qr, Kr, Vt, Ob);

  gemm_nt<EPI_OUT><<<dim3(16, 32), 256, 0, stream>>>(
      Ob, Wob, nullptr, nullptr, nullptr, nullptr, nullptr, out, 2048);
}

// Round 6
// 321.355 us; speedup vs baseline: 1.1174x; 1.0161x over previous
//
#include <hip/hip_runtime.h>

typedef unsigned short u16;
typedef __attribute__((ext_vector_type(8))) short s16x8;
typedef __attribute__((ext_vector_type(4))) float f32x4;
typedef __attribute__((ext_vector_type(16))) float f32x16;
typedef __attribute__((ext_vector_type(4))) unsigned short u16x4;
typedef __attribute__((ext_vector_type(4))) unsigned int u32x4;

#define MFMA16(a, b, c) __builtin_amdgcn_mfma_f32_16x16x32_bf16(a, b, c, 0, 0, 0)
#define MFMA32(a, b, c) __builtin_amdgcn_mfma_f32_32x32x16_bf16(a, b, c, 0, 0, 0)

__device__ __forceinline__ u16 f2bf(float f) {
  unsigned u = __builtin_bit_cast(unsigned, f);
  u += 0x7fffu + ((u >> 16) & 1u);  // RNE
  return (u16)(u >> 16);
}

__device__ __forceinline__ void async16(const void* g, void* l) {
  __builtin_amdgcn_global_load_lds(
      (const __attribute__((address_space(1))) void*)g,
      (__attribute__((address_space(3))) void*)l, 16, 0, 0);
}

__device__ __forceinline__ s16x8 ld8(const u16* p) { return *(const s16x8*)p; }

// packed f32x2 -> bf16x2 (RNE); no builtin on gfx950, inline asm per T12
__device__ __forceinline__ unsigned cvtpk(float lo, float hi) {
  unsigned r;
  asm("v_cvt_pk_bf16_f32 %0, %1, %2" : "=v"(r) : "v"(lo), "v"(hi));
  return r;
}

// log2(e) / sqrt(64) folded into Q at projection time
#define PRE 0.18033688011112042f

// ---------------- fused fp32 -> bf16 cast of all 5 tensors ----------------
__global__ __launch_bounds__(256) void cvt_all(
    const float* __restrict__ X, const float* __restrict__ Wq,
    const float* __restrict__ Wk, const float* __restrict__ Wv,
    const float* __restrict__ Wo, u16* __restrict__ out) {
  long e = (long)(blockIdx.x * 256 + threadIdx.x) * 4;
  const float* src;
  if (e < 8388608L) src = X + e;
  else if (e < 12582912L) src = Wq + (e - 8388608L);
  else if (e < 13631488L) src = Wk + (e - 12582912L);
  else if (e < 14680064L) src = Wv + (e - 13631488L);
  else src = Wo + (e - 14680064L);
  float4 v = *(const float4*)src;
  u16x4 o = {f2bf(v.x), f2bf(v.y), f2bf(v.z), f2bf(v.w)};
  *(u16x4*)(out + e) = o;
}

// ---------------- NT GEMM: C[m,n] = sum_k A[m,k]*B[n,k] ----------------
// 128x128 tile, BK=32, double-buffered LDS, ONE barrier per K-iter (prefetch
// issued right after the barrier -> a full compute phase to land before the
// next barrier's vmcnt drain). Tiles stored as 64 double-rows x 8 XOR-swizzled
// 16B chunks (conflict-free family).  [round-1 verified @78.5us QKV, 656 TF;
// counted-vmcnt grafts on this 2-barrier structure measured null (m131, r3);
// 256^2-tile variants underfill the 256-CU grid and lose (r3)]
//
// Round-6: Q/K rope epilogue vectorized. The old path did 64 scattered 2B
// global stores per thread (each wave-store touches 64 distinct 128B lines).
// Now: rope in f32 registers (numerics unchanged) -> roped bf16 into a
// wave-private 8KB LDS region [64 rows][64 d], chunk-XOR swizzle
// d ^ ((row&7)<<3) -> 8 x ld8 + 8 x fully-coalesced 16B stores (1KB/instr).
enum { EPI_QKV = 0, EPI_OUT = 1 };

template <int EPI>
__global__ __launch_bounds__(256) void gemm_nt(
    const u16* __restrict__ A, const u16* __restrict__ Bm,
    const float* __restrict__ cosp, const float* __restrict__ sinp,
    u16* __restrict__ Qo, u16* __restrict__ Ko, u16* __restrict__ Vo,
    float* __restrict__ Co, int K) {
  // [2 buffers][A: 4096 u16 | B: 4096 u16] = 32 KB; epilogue reuses all 32 KB
  __shared__ u16 SM[16384];
  const int t = threadIdx.x;
  const int lane = t & 63;
  const int w = t >> 6, wm = w >> 1, wn = w & 1;
  const int quad = lane >> 4, c16 = lane & 15;
  const int m0 = blockIdx.y * 128, n0 = blockIdx.x * 128;

  f32x4 acc[4][4];
  const f32x4 zero = {0.f, 0.f, 0.f, 0.f};
#pragma unroll
  for (int i = 0; i < 4; ++i)
#pragma unroll
    for (int j = 0; j < 4; ++j) acc[i][j] = zero;

  // staging: chunk c (16B) of a 128x32 tile holds global
  //   double-row dr=c>>3, k8=(c&7)^(dr&7) -> (row 2dr+(k8>>2), colchunk k8&3)
  const u16* gA[2];
  const u16* gB[2];
  int lof[2];
#pragma unroll
  for (int p = 0; p < 2; ++p) {
    int c = t + p * 256;
    int dr = c >> 3, k8 = (c & 7) ^ (dr & 7);
    int row = 2 * dr + (k8 >> 2), col = (k8 & 3) * 8;
    gA[p] = A + (size_t)(m0 + row) * K + col;
    gB[p] = Bm + (size_t)(n0 + row) * K + col;
    lof[p] = c * 8;  // u16 index within a buffer half
  }

  // fragment LDS offsets (loop-invariant; toggle buffer by +8192)
  int aoff[4], boff[4];
#pragma unroll
  for (int i = 0; i < 4; ++i) {
    int rowA = wm * 64 + i * 16 + c16;
    int drA = rowA >> 1;
    int chA = (((rowA & 1) << 2) | quad) ^ (drA & 7);
    aoff[i] = drA * 64 + chA * 8;
    int rowB = wn * 64 + i * 16 + c16;
    int drB = rowB >> 1;
    int chB = (((rowB & 1) << 2) | quad) ^ (drB & 7);
    boff[i] = 4096 + drB * 64 + chB * 8;
  }

  // prologue: stage buffer 0 with k-slab 0
#pragma unroll
  for (int p = 0; p < 2; ++p) {
    async16(gA[p], &SM[lof[p]]);
    async16(gB[p], &SM[4096 + lof[p]]);
  }

  const int niter = K >> 5;
  for (int kt = 0; kt < niter; ++kt) {
    const int cb = (kt & 1) * 8192;
    __syncthreads();  // drains vmcnt: buf[cur] staged; prev reads of buf[nxt] done
    if (kt + 1 < niter) {
      const int nb = 8192 - cb;
#pragma unroll
      for (int p = 0; p < 2; ++p) {
        gA[p] += 32;
        gB[p] += 32;
        async16(gA[p], &SM[nb + lof[p]]);
        async16(gB[p], &SM[nb + 4096 + lof[p]]);
      }
    }
    s16x8 af[4], bfr[4];
#pragma unroll
    for (int i = 0; i < 4; ++i) af[i] = ld8(&SM[cb + aoff[i]]);
#pragma unroll
    for (int j = 0; j < 4; ++j) bfr[j] = ld8(&SM[cb + boff[j]]);
#pragma unroll
    for (int i = 0; i < 4; ++i)
#pragma unroll
      for (int j = 0; j < 4; ++j) acc[i][j] = MFMA16(af[i], bfr[j], acc[i][j]);
  }

  if (EPI == EPI_OUT) {
#pragma unroll
    for (int i = 0; i < 4; ++i)
#pragma unroll
      for (int r = 0; r < 4; ++r) {
        int m = m0 + wm * 64 + i * 16 + quad * 4 + r;
        float* dst = Co + (size_t)m * 2048 + n0 + wn * 64 + c16;
#pragma unroll
        for (int j = 0; j < 4; ++j) dst[j * 16] = acc[i][j][r];
      }
  } else if (n0 >= 2560) {
    // V zone: transpose via LDS -> coalesced 16B stores of V^T [B][8][64][S]
    __syncthreads();  // all K-loop LDS reads done before overwrite
#pragma unroll
    for (int i = 0; i < 4; ++i)
#pragma unroll
      for (int r = 0; r < 4; ++r) {
        int sl = wm * 64 + i * 16 + quad * 4 + r;
#pragma unroll
        for (int j = 0; j < 4; ++j) {
          int dl = wn * 64 + j * 16 + c16;
          SM[dl * 128 + (((sl >> 3) ^ (dl & 15)) * 8) + (sl & 7)] =
              f2bf(acc[i][j][r]);
        }
      }
    __syncthreads();
    int bb = m0 >> 11, m0s = m0 & 2047;
#pragma unroll
    for (int p = 0; p < 8; ++p) {
      int q = p * 256 + t;
      int dl = q >> 4, k = q & 15;
      s16x8 vrow = ld8(&SM[dl * 128 + ((k ^ (dl & 15)) * 8)]);
      int nab = n0 + dl;
      int kvh = (nab - 2560) >> 6, dh = nab & 63;
      *(s16x8*)(Vo + ((size_t)(bb * 8 + kvh) * 64 + dh) * 2048 + m0s + k * 8) =
          vrow;
    }
  } else {
    // Q / K zone: rope in f32 registers (numerics identical to round 1-5),
    // roped bf16 -> wave-private LDS [64 rows][64 d] (swizzled), then 8 fully
    // coalesced 16B stores/thread instead of 64 scattered 2B stores.
    const int nbase = n0 + wn * 64;  // wave-uniform; 64-wide = one head
    const bool isQ = (nbase < 2048);
    const int h = isQ ? (nbase >> 6) : ((nbase - 2048) >> 6);
    u16* const dstT = isQ ? Qo : Ko;
    const int NH = isQ ? 32 : 8;
    const float pre = isQ ? PRE : 1.0f;
    __syncthreads();  // all waves' K-loop LDS reads done before overwrite
    u16* const Wl = SM + w * 4096;  // wave-private 8KB
#pragma unroll
    for (int i = 0; i < 4; ++i)
#pragma unroll
      for (int r = 0; r < 4; ++r) {
        int rl = i * 16 + quad * 4 + r;  // row_local 0..63
        int m = m0 + wm * 64 + rl;
        int swz = (rl & 7) << 3;
#pragma unroll
        for (int j = 0; j < 2; ++j) {
          int d = j * 16 + c16;
          float v1 = acc[i][j][r], v2 = acc[i][j + 2][r];
          float c1 = cosp[m * 64 + d], s1 = sinp[m * 64 + d];
          float c2 = cosp[m * 64 + d + 32], s2 = sinp[m * 64 + d + 32];
          Wl[rl * 64 + (d ^ swz)] = f2bf((v1 * c1 - v2 * s1) * pre);
          Wl[rl * 64 + ((d + 32) ^ swz)] = f2bf((v2 * c2 + v1 * s2) * pre);
        }
      }
    // wave-private region: in-wave lgkmcnt ordering suffices, no barrier
#pragma unroll
    for (int p = 0; p < 8; ++p) {
      int q = p * 64 + lane;
      int rl = q >> 3, ck = q & 7;
      s16x8 vrow = ld8(&Wl[rl * 64 + ((ck ^ (rl & 7)) * 8)]);
      int m = m0 + wm * 64 + rl;
      int b = m >> 11, s = m & 2047;
      *(s16x8*)(dstT + ((size_t)(b * NH + h) * 2048 + s) * 64 + ck * 8) = vrow;
    }
  }
}

// ---------------- flash attention (causal, GQA) ----------------
// grid: (8 qt-pairs, 64 b*h). Each block does q-tiles {x, 15-x}: exactly 34
// k-iters -> PERFECT load balance (round-4 un-pairing gave a 17x work spread
// with no backfill slack and regressed 77->122us; pairing restored).
// BQ=128 (4 waves x 32 rows), BKV=64. Double-buffered K/V, ONE barrier/iter.
// Swapped-operand 32x32x16 MFMA (S^T = mfma(K,Q)) + fully in-register P via
// T12 (cvt_pk_bf16 + permlane32_swap). Fixed-m (m=0) online softmax;
// l-reduction deferred to epilogue.
// Round-5 ILP batching of both kn half-tiles retained (rule #20: all static).
__global__ __launch_bounds__(256) void attn(const u16* __restrict__ Q,
                                            const u16* __restrict__ Kg,
                                            const u16* __restrict__ Vg,
                                            u16* __restrict__ O) {
  __shared__ u16 Ks[2][4096];   // [buf][64 keys][64 d], XOR-swizzled chunks
  __shared__ u16 Vs[2][4096];   // [buf][64 d][64 keys] (V^T), same swizzle
  __shared__ float Lred[128];   // per-wave 1/l broadcast (32 floats/wave)
  const int t = threadIdx.x;
  const int lane = t & 63;
  const int w = t >> 6;
  const int l31 = lane & 31, hi = lane >> 5;
  const int bh = blockIdx.y;
  const int b = bh >> 5, h = bh & 31;
  const int kvh = h >> 2;  // G = 4

  const u16* Qbase = Q + ((size_t)(b * 32 + h) * 2048) * 64;
  const u16* Kbase = Kg + ((size_t)(b * 8 + kvh) * 2048) * 64;
  const u16* Vbase = Vg + ((size_t)(b * 8 + kvh) * 64) * 2048;

  const int sr0 = t >> 3, sc0 = ((t & 7) ^ (sr0 & 7)) * 8;
  const int sr1 = (t + 256) >> 3, sc1 = (((t + 256) & 7) ^ (sr1 & 7)) * 8;

  int off8[4];
#pragma unroll
  for (int c = 0; c < 4; ++c) off8[c] = ((2 * c + hi) ^ (l31 & 7)) * 8;
  const int rbB = l31 * 64;

  for (int ph = 0; ph < 2; ++ph) {
    const int qt = ph ? 15 - blockIdx.x : blockIdx.x;
    const int q0 = qt * 128;
    const int rbase = q0 + w * 32;
    const int qrow = rbase + l31;  // this lane's q-row (S^T column)

    s16x8 qf[4];
#pragma unroll
    for (int dc = 0; dc < 4; ++dc)
      qf[dc] = ld8(Qbase + (size_t)qrow * 64 + dc * 16 + hi * 8);

    f32x16 oacc[2];
#pragma unroll
    for (int dn = 0; dn < 2; ++dn)
#pragma unroll
      for (int r = 0; r < 16; ++r) oacc[dn][r] = 0.f;
    float lacc = 0.f;

    const int nkt = 2 * qt + 2;

    __syncthreads();  // previous phase's LDS reads done before restaging buf0
    {
      async16(Kbase + sr0 * 64 + sc0, &Ks[0][t * 8]);
      async16(Kbase + sr1 * 64 + sc1, &Ks[0][t * 8 + 2048]);
      async16(Vbase + (size_t)sr0 * 2048 + sc0, &Vs[0][t * 8]);
      async16(Vbase + (size_t)sr1 * 2048 + sc1, &Vs[0][t * 8 + 2048]);
    }

    for (int kt = 0; kt < nkt; ++kt) {
      const int cur = kt & 1;
      __syncthreads();  // buf[cur] staged; prev reads of buf[1-cur] done
      if (kt + 1 < nkt) {
        const int nxt = 1 - cur;
        const u16* kg = Kbase + (kt + 1) * 4096;
        async16(kg + sr0 * 64 + sc0, &Ks[nxt][t * 8]);
        async16(kg + sr1 * 64 + sc1, &Ks[nxt][t * 8 + 2048]);
        async16(Vbase + (size_t)sr0 * 2048 + (kt + 1) * 64 + sc0,
                &Vs[nxt][t * 8]);
        async16(Vbase + (size_t)sr1 * 2048 + (kt + 1) * 64 + sc1,
                &Vs[nxt][t * 8 + 2048]);
      }
      const u16* Kb = Ks[cur];
      const u16* Vb = Vs[cur];

      const int kb0 = kt * 64;
      const bool do0 = (kb0 <= rbase + 31);       // kn=0 half-tile live
      const bool do1 = (kb0 + 32 <= rbase + 31);  // kn=1 half-tile live
      if (do0) {
        // --- both QK^T chains issued back-to-back (independent accs) ---
        f32x16 s0, s1;
#pragma unroll
        for (int r = 0; r < 16; ++r) s0[r] = 0.f;
#pragma unroll
        for (int r = 0; r < 16; ++r) s1[r] = 0.f;
        __builtin_amdgcn_s_setprio(1);
#pragma unroll
        for (int dc = 0; dc < 4; ++dc) {
          s16x8 kf = ld8(&Kb[rbB + off8[dc]]);
          s0 = MFMA32(kf, qf[dc], s0);
        }
        if (do1) {
#pragma unroll
          for (int dc = 0; dc < 4; ++dc) {
            s16x8 kf = ld8(&Kb[2048 + rbB + off8[dc]]);
            s1 = MFMA32(kf, qf[dc], s1);
          }
        }
        __builtin_amdgcn_s_setprio(0);
        // --- causal masks (diagonal tiles only; wave-uniform branches) ---
        if (kb0 + 31 > rbase) {
          const int kb = kb0 + 4 * hi;
#pragma unroll
          for (int r = 0; r < 16; ++r)
            if (kb + (r & 3) + 8 * (r >> 2) > qrow) s0[r] = -1e30f;
        }
        if (do1 && kb0 + 63 > rbase) {
          const int kb = kb0 + 32 + 4 * hi;
#pragma unroll
          for (int r = 0; r < 16; ++r)
            if (kb + (r & 3) + 8 * (r >> 2) > qrow) s1[r] = -1e30f;
        }
        // --- 16/32 independent exp2 ---
        float p0[16], p1[16];
#pragma unroll
        for (int r = 0; r < 16; ++r) p0[r] = __builtin_amdgcn_exp2f(s0[r]);
        if (do1) {
#pragma unroll
          for (int r = 0; r < 16; ++r) p1[r] = __builtin_amdgcn_exp2f(s1[r]);
        }
        // --- l accumulation (balanced trees) ---
        {
          float e0 = p0[0] + p0[1], e1 = p0[2] + p0[3], e2 = p0[4] + p0[5],
                e3 = p0[6] + p0[7], e4 = p0[8] + p0[9], e5 = p0[10] + p0[11],
                e6 = p0[12] + p0[13], e7 = p0[14] + p0[15];
          lacc += ((e0 + e1) + (e2 + e3)) + ((e4 + e5) + (e6 + e7));
        }
        if (do1) {
          float e0 = p1[0] + p1[1], e1 = p1[2] + p1[3], e2 = p1[4] + p1[5],
                e3 = p1[6] + p1[7], e4 = p1[8] + p1[9], e5 = p1[10] + p1[11],
                e6 = p1[12] + p1[13], e7 = p1[14] + p1[15];
          lacc += ((e0 + e1) + (e2 + e3)) + ((e4 + e5) + (e6 + e7));
        }
        // --- T12 fragment builds for all live kk ---
        s16x8 F0, F1, F2, F3;
        {
          unsigned a0 = cvtpk(p0[0], p0[1]), b0 = cvtpk(p0[4], p0[5]);
          unsigned a1 = cvtpk(p0[2], p0[3]), b1 = cvtpk(p0[6], p0[7]);
          auto s0s = __builtin_amdgcn_permlane32_swap(a0, b0, false, false);
          auto s1s = __builtin_amdgcn_permlane32_swap(a1, b1, false, false);
          u32x4 fw = {(unsigned)s0s[0], (unsigned)s1s[0], (unsigned)s0s[1],
                      (unsigned)s1s[1]};
          F0 = __builtin_bit_cast(s16x8, fw);
          unsigned a2 = cvtpk(p0[8], p0[9]), b2 = cvtpk(p0[12], p0[13]);
          unsigned a3 = cvtpk(p0[10], p0[11]), b3 = cvtpk(p0[14], p0[15]);
          auto s2s = __builtin_amdgcn_permlane32_swap(a2, b2, false, false);
          auto s3s = __builtin_amdgcn_permlane32_swap(a3, b3, false, false);
          u32x4 fw2 = {(unsigned)s2s[0], (unsigned)s3s[0], (unsigned)s2s[1],
                       (unsigned)s3s[1]};
          F1 = __builtin_bit_cast(s16x8, fw2);
        }
        if (do1) {
          unsigned a0 = cvtpk(p1[0], p1[1]), b0 = cvtpk(p1[4], p1[5]);
          unsigned a1 = cvtpk(p1[2], p1[3]), b1 = cvtpk(p1[6], p1[7]);
          auto s0s = __builtin_amdgcn_permlane32_swap(a0, b0, false, false);
          auto s1s = __builtin_amdgcn_permlane32_swap(a1, b1, false, false);
          u32x4 fw = {(unsigned)s0s[0], (unsigned)s1s[0], (unsigned)s0s[1],
                      (unsigned)s1s[1]};
          F2 = __builtin_bit_cast(s16x8, fw);
          unsigned a2 = cvtpk(p1[8], p1[9]), b2 = cvtpk(p1[12], p1[13]);
          unsigned a3 = cvtpk(p1[10], p1[11]), b3 = cvtpk(p1[14], p1[15]);
          auto s2s = __builtin_amdgcn_permlane32_swap(a2, b2, false, false);
          auto s3s = __builtin_amdgcn_permlane32_swap(a3, b3, false, false);
          u32x4 fw2 = {(unsigned)s2s[0], (unsigned)s3s[0], (unsigned)s2s[1],
                       (unsigned)s3s[1]};
          F3 = __builtin_bit_cast(s16x8, fw2);
        }
        // --- all PV MFMAs, alternating accumulators (dep distance 2) ---
        __builtin_amdgcn_s_setprio(1);
#pragma unroll
        for (int dn = 0; dn < 2; ++dn) {
          s16x8 vf = ld8(&Vb[dn * 2048 + rbB + off8[0]]);
          oacc[dn] = MFMA32(F0, vf, oacc[dn]);
        }
#pragma unroll
        for (int dn = 0; dn < 2; ++dn) {
          s16x8 vf = ld8(&Vb[dn * 2048 + rbB + off8[1]]);
          oacc[dn] = MFMA32(F1, vf, oacc[dn]);
        }
        if (do1) {
#pragma unroll
          for (int dn = 0; dn < 2; ++dn) {
            s16x8 vf = ld8(&Vb[dn * 2048 + rbB + off8[2]]);
            oacc[dn] = MFMA32(F2, vf, oacc[dn]);
          }
#pragma unroll
          for (int dn = 0; dn < 2; ++dn) {
            s16x8 vf = ld8(&Vb[dn * 2048 + rbB + off8[3]]);
            oacc[dn] = MFMA32(F3, vf, oacc[dn]);
          }
        }
        __builtin_amdgcn_s_setprio(0);
      }
    }

    // epilogue: l split across hi halves -> one shfl_xor(32), broadcast 1/l
    // through wave-private LDS, scale + store O
    {
      float ltot = lacc + __shfl_xor(lacc, 32);
      if (lane < 32) Lred[w * 32 + l31] = 1.f / ltot;
      f32x4 lv[4];
#pragma unroll
      for (int g = 0; g < 4; ++g)
        lv[g] = *(const f32x4*)&Lred[w * 32 + 8 * g + 4 * hi];
#pragma unroll
      for (int dn = 0; dn < 2; ++dn)
#pragma unroll
        for (int g = 0; g < 4; ++g)
#pragma unroll
          for (int j = 0; j < 4; ++j) {
            int s = rbase + 8 * g + 4 * hi + j;
            O[((size_t)(b * 2048 + s)) * 2048 + h * 64 + dn * 32 + l31] =
                f2bf(oacc[dn][4 * g + j] * lv[g][j]);
          }
    }
  }
}

// ---------------- launch ----------------
extern "C" void kernel_launch(void* const* d_in, const int* in_sizes, int n_in,
                              void* d_out, int out_size, void* d_ws,
                              size_t ws_size, hipStream_t stream) {
  const float* X = (const float*)d_in[0];
  const float* cosp = (const float*)d_in[1];
  const float* sinp = (const float*)d_in[2];
  const float* Wq = (const float*)d_in[4];
  const float* Wk = (const float*)d_in[5];
  const float* Wv = (const float*)d_in[6];
  const float* Wo = (const float*)d_in[7];
  float* out = (float*)d_out;

  u16* Xb = (u16*)d_ws;       // 8,388,608
  u16* Wqkv = Xb + 8388608;   // 3072x2048 (Wq|Wk|Wv rows)
  u16* Wob = Wqkv + 6291456;  // 4,194,304
  u16* Qr = Wob + 4194304;    // [2][32][2048][64]  (pre-scaled)
  u16* Kr = Qr + 8388608;     // [2][8][2048][64]
  u16* Vt = Kr + 2097152;     // [2][8][64][2048]
  u16* Ob = Vt + 2097152;     // [2][2048][2048]

  cvt_all<<<18432, 256, 0, stream>>>(X, Wq, Wk, Wv, Wo, Xb);

  gemm_nt<EPI_QKV><<<dim3(24, 32), 256, 0, stream>>>(
      Xb, Wqkv, cosp, sinp, Qr, Kr, Vt, nullptr, 2048);

  attn<<<dim3(8, 64), 256, 0, stream>>>(Qr, Kr, Vt, Ob);

  gemm_nt<EPI_OUT><<<dim3(16, 32), 256, 0, stream>>>(
      Ob, Wob, nullptr, nullptr, nullptr, nullptr, nullptr, out, 2048);
}

// Round 7
// 308.784 us; speedup vs baseline: 1.1629x; 1.0407x over previous
//
#include <hip/hip_runtime.h>

typedef unsigned short u16;
typedef __attribute__((ext_vector_type(8))) short s16x8;
typedef __attribute__((ext_vector_type(4))) float f32x4;
typedef __attribute__((ext_vector_type(16))) float f32x16;
typedef __attribute__((ext_vector_type(4))) unsigned short u16x4;
typedef __attribute__((ext_vector_type(4))) unsigned int u32x4;

#define MFMA16(a, b, c) __builtin_amdgcn_mfma_f32_16x16x32_bf16(a, b, c, 0, 0, 0)
#define MFMA32(a, b, c) __builtin_amdgcn_mfma_f32_32x32x16_bf16(a, b, c, 0, 0, 0)

__device__ __forceinline__ u16 f2bf(float f) {
  unsigned u = __builtin_bit_cast(unsigned, f);
  u += 0x7fffu + ((u >> 16) & 1u);  // RNE
  return (u16)(u >> 16);
}

__device__ __forceinline__ void async16(const void* g, void* l) {
  __builtin_amdgcn_global_load_lds(
      (const __attribute__((address_space(1))) void*)g,
      (__attribute__((address_space(3))) void*)l, 16, 0, 0);
}

__device__ __forceinline__ s16x8 ld8(const u16* p) { return *(const s16x8*)p; }

// packed f32x2 -> bf16x2 (RNE); no builtin on gfx950, inline asm per T12
__device__ __forceinline__ unsigned cvtpk(float lo, float hi) {
  unsigned r;
  asm("v_cvt_pk_bf16_f32 %0, %1, %2" : "=v"(r) : "v"(lo), "v"(hi));
  return r;
}

// log2(e) / sqrt(64) folded into Q at projection time
#define PRE 0.18033688011112042f

// ---------------- fused fp32 -> bf16 cast of all 5 tensors ----------------
__global__ __launch_bounds__(256) void cvt_all(
    const float* __restrict__ X, const float* __restrict__ Wq,
    const float* __restrict__ Wk, const float* __restrict__ Wv,
    const float* __restrict__ Wo, u16* __restrict__ out) {
  long e = (long)(blockIdx.x * 256 + threadIdx.x) * 4;
  const float* src;
  if (e < 8388608L) src = X + e;
  else if (e < 12582912L) src = Wq + (e - 8388608L);
  else if (e < 13631488L) src = Wk + (e - 12582912L);
  else if (e < 14680064L) src = Wv + (e - 13631488L);
  else src = Wo + (e - 14680064L);
  float4 v = *(const float4*)src;
  u16x4 o = {f2bf(v.x), f2bf(v.y), f2bf(v.z), f2bf(v.w)};
  *(u16x4*)(out + e) = o;
}

// ---------------- NT GEMM: C[m,n] = sum_k A[m,k]*B[n,k] ----------------
// 128x128 tile, BK=32, double-buffered LDS, ONE barrier per K-iter. Tiles
// stored as 64 double-rows x 8 XOR-swizzled 16B chunks (conflict-free).
// [round-1 verified @78.5us QKV, 656 TF. Negative results on this kernel:
//  counted-vmcnt graft (r3), 256^2 tiles (r3: grid underfill), Q/K epilogue
//  LDS-transpose (r6: scattered 2B async stores were FREE at 17% HBM; the
//  LDS round-trip cost 8us). Keep the scattered-store epilogue.]
enum { EPI_QKV = 0, EPI_OUT = 1 };

template <int EPI>
__global__ __launch_bounds__(256) void gemm_nt(
    const u16* __restrict__ A, const u16* __restrict__ Bm,
    const float* __restrict__ cosp, const float* __restrict__ sinp,
    u16* __restrict__ Qo, u16* __restrict__ Ko, u16* __restrict__ Vo,
    float* __restrict__ Co, int K) {
  // [2 buffers][A: 4096 u16 | B: 4096 u16] = 32 KB; epilogue reuses all 32 KB
  __shared__ u16 SM[16384];
  const int t = threadIdx.x;
  const int lane = t & 63;
  const int w = t >> 6, wm = w >> 1, wn = w & 1;
  const int quad = lane >> 4, c16 = lane & 15;
  const int m0 = blockIdx.y * 128, n0 = blockIdx.x * 128;

  f32x4 acc[4][4];
  const f32x4 zero = {0.f, 0.f, 0.f, 0.f};
#pragma unroll
  for (int i = 0; i < 4; ++i)
#pragma unroll
    for (int j = 0; j < 4; ++j) acc[i][j] = zero;

  // staging: chunk c (16B) of a 128x32 tile holds global
  //   double-row dr=c>>3, k8=(c&7)^(dr&7) -> (row 2dr+(k8>>2), colchunk k8&3)
  const u16* gA[2];
  const u16* gB[2];
  int lof[2];
#pragma unroll
  for (int p = 0; p < 2; ++p) {
    int c = t + p * 256;
    int dr = c >> 3, k8 = (c & 7) ^ (dr & 7);
    int row = 2 * dr + (k8 >> 2), col = (k8 & 3) * 8;
    gA[p] = A + (size_t)(m0 + row) * K + col;
    gB[p] = Bm + (size_t)(n0 + row) * K + col;
    lof[p] = c * 8;  // u16 index within a buffer half
  }

  // fragment LDS offsets (loop-invariant; toggle buffer by +8192)
  int aoff[4], boff[4];
#pragma unroll
  for (int i = 0; i < 4; ++i) {
    int rowA = wm * 64 + i * 16 + c16;
    int drA = rowA >> 1;
    int chA = (((rowA & 1) << 2) | quad) ^ (drA & 7);
    aoff[i] = drA * 64 + chA * 8;
    int rowB = wn * 64 + i * 16 + c16;
    int drB = rowB >> 1;
    int chB = (((rowB & 1) << 2) | quad) ^ (drB & 7);
    boff[i] = 4096 + drB * 64 + chB * 8;
  }

  // prologue: stage buffer 0 with k-slab 0
#pragma unroll
  for (int p = 0; p < 2; ++p) {
    async16(gA[p], &SM[lof[p]]);
    async16(gB[p], &SM[4096 + lof[p]]);
  }

  const int niter = K >> 5;
  for (int kt = 0; kt < niter; ++kt) {
    const int cb = (kt & 1) * 8192;
    __syncthreads();  // drains vmcnt: buf[cur] staged; prev reads of buf[nxt] done
    if (kt + 1 < niter) {
      const int nb = 8192 - cb;
#pragma unroll
      for (int p = 0; p < 2; ++p) {
        gA[p] += 32;
        gB[p] += 32;
        async16(gA[p], &SM[nb + lof[p]]);
        async16(gB[p], &SM[nb + 4096 + lof[p]]);
      }
    }
    s16x8 af[4], bfr[4];
#pragma unroll
    for (int i = 0; i < 4; ++i) af[i] = ld8(&SM[cb + aoff[i]]);
#pragma unroll
    for (int j = 0; j < 4; ++j) bfr[j] = ld8(&SM[cb + boff[j]]);
#pragma unroll
    for (int i = 0; i < 4; ++i)
#pragma unroll
      for (int j = 0; j < 4; ++j) acc[i][j] = MFMA16(af[i], bfr[j], acc[i][j]);
  }

  if (EPI == EPI_OUT) {
#pragma unroll
    for (int i = 0; i < 4; ++i)
#pragma unroll
      for (int r = 0; r < 4; ++r) {
        int m = m0 + wm * 64 + i * 16 + quad * 4 + r;
        float* dst = Co + (size_t)m * 2048 + n0 + wn * 64 + c16;
#pragma unroll
        for (int j = 0; j < 4; ++j) dst[j * 16] = acc[i][j][r];
      }
  } else if (n0 >= 2560) {
    // V zone: transpose via LDS -> coalesced 16B stores of V^T [B][8][64][S]
    __syncthreads();  // all K-loop LDS reads done before overwrite
#pragma unroll
    for (int i = 0; i < 4; ++i)
#pragma unroll
      for (int r = 0; r < 4; ++r) {
        int sl = wm * 64 + i * 16 + quad * 4 + r;
#pragma unroll
        for (int j = 0; j < 4; ++j) {
          int dl = wn * 64 + j * 16 + c16;
          SM[dl * 128 + (((sl >> 3) ^ (dl & 15)) * 8) + (sl & 7)] =
              f2bf(acc[i][j][r]);
        }
      }
    __syncthreads();
    int bb = m0 >> 11, m0s = m0 & 2047;
#pragma unroll
    for (int p = 0; p < 8; ++p) {
      int q = p * 256 + t;
      int dl = q >> 4, k = q & 15;
      s16x8 vrow = ld8(&SM[dl * 128 + ((k ^ (dl & 15)) * 8)]);
      int nab = n0 + dl;
      int kvh = (nab - 2560) >> 6, dh = nab & 63;
      *(s16x8*)(Vo + ((size_t)(bb * 8 + kvh) * 64 + dh) * 2048 + m0s + k * 8) =
          vrow;
    }
  } else {
    const int nbase = n0 + wn * 64;
#pragma unroll
    for (int i = 0; i < 4; ++i)
#pragma unroll
      for (int r = 0; r < 4; ++r) {
        int m = m0 + wm * 64 + i * 16 + quad * 4 + r;
        int b = m >> 11, s = m & 2047;
        if (nbase < 2048) {  // Q zone: rope + prescale, store [B][32][S][64]
          int h = nbase >> 6;
          size_t base = ((size_t)(b * 32 + h) * 2048 + s) * 64;
#pragma unroll
          for (int j = 0; j < 2; ++j) {
            int d = j * 16 + c16;
            float v1 = acc[i][j][r], v2 = acc[i][j + 2][r];
            float c1 = cosp[m * 64 + d], s1 = sinp[m * 64 + d];
            float c2 = cosp[m * 64 + d + 32], s2 = sinp[m * 64 + d + 32];
            Qo[base + d] = f2bf((v1 * c1 - v2 * s1) * PRE);
            Qo[base + d + 32] = f2bf((v2 * c2 + v1 * s2) * PRE);
          }
        } else {  // K zone: rope, store [B][8][S][64]
          int h = (nbase - 2048) >> 6;
          size_t base = ((size_t)(b * 8 + h) * 2048 + s) * 64;
#pragma unroll
          for (int j = 0; j < 2; ++j) {
            int d = j * 16 + c16;
            float v1 = acc[i][j][r], v2 = acc[i][j + 2][r];
            float c1 = cosp[m * 64 + d], s1 = sinp[m * 64 + d];
            float c2 = cosp[m * 64 + d + 32], s2 = sinp[m * 64 + d + 32];
            Ko[base + d] = f2bf(v1 * c1 - v2 * s1);
            Ko[base + d + 32] = f2bf(v2 * c2 + v1 * s2);
          }
        }
      }
  }
}

// ---------------- flash attention (causal, GQA) ----------------
// grid: (8 qt-pairs, 64 b*h). Each block does q-tiles {x, 15-x}: perfect
// load balance (r4: un-pairing = 17x work spread, regressed).
// BQ=128 (4 waves x 32 rows).
//
// Round-7: KVBLK 64 -> 128. attn is barrier-drain-bound (all pipes <60%,
// 2 blocks/CU grid-limited); each __syncthreads costs a full vmcnt drain.
// 128-key tiles halve the barrier count (34 -> 17 per block) and double the
// compute phase covering each prefetch. LDS 66KB still fits 2 blocks/CU
// (grid-limited anyway). Inner math = r5 batch body run twice (bs=0,1),
// all indexing compile-time-static (rule #20).
// K LDS [128 keys][64 d]: 8 chunks/row, slot = chunk ^ (row&7) (rows%8
// structure unchanged). V LDS [64 d][128 keys]: 16 chunks/row, slot =
// chunk ^ (row&15); staging source pre-swizzled to match (rule #21).
// Swapped-operand 32x32x16 MFMA (S^T = mfma(K,Q)) + in-register P via T12.
// Fixed-m (m=0) online softmax; l-reduction deferred to epilogue.
__global__ __launch_bounds__(256) void attn(const u16* __restrict__ Q,
                                            const u16* __restrict__ Kg,
                                            const u16* __restrict__ Vg,
                                            u16* __restrict__ O) {
  __shared__ u16 Ks[2][8192];   // [buf][128 keys][64 d], XOR-swizzled chunks
  __shared__ u16 Vs[2][8192];   // [buf][64 d][128 keys] (V^T), 16-chunk swz
  __shared__ float Lred[128];   // per-wave 1/l broadcast (32 floats/wave)
  const int t = threadIdx.x;
  const int lane = t & 63;
  const int w = t >> 6;
  const int l31 = lane & 31, hi = lane >> 5;
  const int bh = blockIdx.y;
  const int b = bh >> 5, h = bh & 31;
  const int kvh = h >> 2;  // G = 4

  const u16* Qbase = Q + ((size_t)(b * 32 + h) * 2048) * 64;
  const u16* Kbase = Kg + ((size_t)(b * 8 + kvh) * 2048) * 64;
  const u16* Vbase = Vg + ((size_t)(b * 8 + kvh) * 64) * 2048;

  // staging precompute: thread covers 4 K-chunks + 4 V-chunks per tile
  int kro[4], kco[4], vro[4], vco[4];
#pragma unroll
  for (int p = 0; p < 4; ++p) {
    int c = t + p * 256;
    kro[p] = c >> 3;
    kco[p] = ((c & 7) ^ (kro[p] & 7)) * 8;
    vro[p] = c >> 4;
    vco[p] = ((c & 15) ^ (vro[p] & 15)) * 8;
  }

  // read-side swizzled chunk offsets
  int off8[4];   // K: chunk 2dc+hi of 8, rows%8-swizzled
#pragma unroll
  for (int c = 0; c < 4; ++c) off8[c] = ((2 * c + hi) ^ (l31 & 7)) * 8;
  int off16[8];  // V: chunk 2kk+hi of 16, rows%16-swizzled
#pragma unroll
  for (int c = 0; c < 8; ++c) off16[c] = ((2 * c + hi) ^ (l31 & 15)) * 8;
  const int rbB = l31 * 64;

  for (int ph = 0; ph < 2; ++ph) {
    const int qt = ph ? 15 - blockIdx.x : blockIdx.x;
    const int q0 = qt * 128;
    const int rbase = q0 + w * 32;
    const int qrow = rbase + l31;  // this lane's q-row (S^T column)

    s16x8 qf[4];
#pragma unroll
    for (int dc = 0; dc < 4; ++dc)
      qf[dc] = ld8(Qbase + (size_t)qrow * 64 + dc * 16 + hi * 8);

    f32x16 oacc[2];
#pragma unroll
    for (int dn = 0; dn < 2; ++dn)
#pragma unroll
      for (int r = 0; r < 16; ++r) oacc[dn][r] = 0.f;
    float lacc = 0.f;

    const int nkt = qt + 1;  // 128-key tiles

    __syncthreads();  // previous phase's LDS reads done before restaging buf0
#pragma unroll
    for (int p = 0; p < 4; ++p) {
      async16(Kbase + (size_t)kro[p] * 64 + kco[p], &Ks[0][(t + p * 256) * 8]);
      async16(Vbase + (size_t)vro[p] * 2048 + vco[p],
              &Vs[0][(t + p * 256) * 8]);
    }

    for (int kt = 0; kt < nkt; ++kt) {
      const int cur = kt & 1;
      __syncthreads();  // buf[cur] staged; prev reads of buf[1-cur] done
      if (kt + 1 < nkt) {
        const int nxt = 1 - cur;
        const u16* kg = Kbase + (size_t)(kt + 1) * 8192;
        const u16* vg = Vbase + (kt + 1) * 128;
#pragma unroll
        for (int p = 0; p < 4; ++p) {
          async16(kg + (size_t)kro[p] * 64 + kco[p],
                  &Ks[nxt][(t + p * 256) * 8]);
          async16(vg + (size_t)vro[p] * 2048 + vco[p],
                  &Vs[nxt][(t + p * 256) * 8]);
        }
      }
      const u16* Kb = Ks[cur];
      const u16* Vb = Vs[cur];

#pragma unroll
      for (int bs = 0; bs < 2; ++bs) {
        const int kb0 = kt * 128 + bs * 64;
        if (kb0 > rbase + 31) continue;  // fully-masked 64-key batch
        const bool dob = (kb0 + 32 <= rbase + 31);
        // --- both QK^T chains issued back-to-back (independent accs) ---
        f32x16 s0, s1;
#pragma unroll
        for (int r = 0; r < 16; ++r) s0[r] = 0.f;
#pragma unroll
        for (int r = 0; r < 16; ++r) s1[r] = 0.f;
        __builtin_amdgcn_s_setprio(1);
#pragma unroll
        for (int dc = 0; dc < 4; ++dc) {
          s16x8 kf = ld8(&Kb[(2 * bs) * 2048 + rbB + off8[dc]]);
          s0 = MFMA32(kf, qf[dc], s0);
        }
        if (dob) {
#pragma unroll
          for (int dc = 0; dc < 4; ++dc) {
            s16x8 kf = ld8(&Kb[(2 * bs + 1) * 2048 + rbB + off8[dc]]);
            s1 = MFMA32(kf, qf[dc], s1);
          }
        }
        __builtin_amdgcn_s_setprio(0);
        // --- causal masks (diagonal tiles only; wave-uniform branches) ---
        if (kb0 + 31 > rbase) {
          const int kb = kb0 + 4 * hi;
#pragma unroll
          for (int r = 0; r < 16; ++r)
            if (kb + (r & 3) + 8 * (r >> 2) > qrow) s0[r] = -1e30f;
        }
        if (dob && kb0 + 63 > rbase) {
          const int kb = kb0 + 32 + 4 * hi;
#pragma unroll
          for (int r = 0; r < 16; ++r)
            if (kb + (r & 3) + 8 * (r >> 2) > qrow) s1[r] = -1e30f;
        }
        // --- independent exp2 ---
        float p0[16], p1[16];
#pragma unroll
        for (int r = 0; r < 16; ++r) p0[r] = __builtin_amdgcn_exp2f(s0[r]);
        if (dob) {
#pragma unroll
          for (int r = 0; r < 16; ++r) p1[r] = __builtin_amdgcn_exp2f(s1[r]);
        }
        // --- l accumulation (balanced trees) ---
        {
          float e0 = p0[0] + p0[1], e1 = p0[2] + p0[3], e2 = p0[4] + p0[5],
                e3 = p0[6] + p0[7], e4 = p0[8] + p0[9], e5 = p0[10] + p0[11],
                e6 = p0[12] + p0[13], e7 = p0[14] + p0[15];
          lacc += ((e0 + e1) + (e2 + e3)) + ((e4 + e5) + (e6 + e7));
        }
        if (dob) {
          float e0 = p1[0] + p1[1], e1 = p1[2] + p1[3], e2 = p1[4] + p1[5],
                e3 = p1[6] + p1[7], e4 = p1[8] + p1[9], e5 = p1[10] + p1[11],
                e6 = p1[12] + p1[13], e7 = p1[14] + p1[15];
          lacc += ((e0 + e1) + (e2 + e3)) + ((e4 + e5) + (e6 + e7));
        }
        // --- T12 fragment builds for all live kk ---
        s16x8 F0, F1, F2, F3;
        {
          unsigned a0 = cvtpk(p0[0], p0[1]), b0 = cvtpk(p0[4], p0[5]);
          unsigned a1 = cvtpk(p0[2], p0[3]), b1 = cvtpk(p0[6], p0[7]);
          auto s0s = __builtin_amdgcn_permlane32_swap(a0, b0, false, false);
          auto s1s = __builtin_amdgcn_permlane32_swap(a1, b1, false, false);
          u32x4 fw = {(unsigned)s0s[0], (unsigned)s1s[0], (unsigned)s0s[1],
                      (unsigned)s1s[1]};
          F0 = __builtin_bit_cast(s16x8, fw);
          unsigned a2 = cvtpk(p0[8], p0[9]), b2 = cvtpk(p0[12], p0[13]);
          unsigned a3 = cvtpk(p0[10], p0[11]), b3 = cvtpk(p0[14], p0[15]);
          auto s2s = __builtin_amdgcn_permlane32_swap(a2, b2, false, false);
          auto s3s = __builtin_amdgcn_permlane32_swap(a3, b3, false, false);
          u32x4 fw2 = {(unsigned)s2s[0], (unsigned)s3s[0], (unsigned)s2s[1],
                       (unsigned)s3s[1]};
          F1 = __builtin_bit_cast(s16x8, fw2);
        }
        if (dob) {
          unsigned a0 = cvtpk(p1[0], p1[1]), b0 = cvtpk(p1[4], p1[5]);
          unsigned a1 = cvtpk(p1[2], p1[3]), b1 = cvtpk(p1[6], p1[7]);
          auto s0s = __builtin_amdgcn_permlane32_swap(a0, b0, false, false);
          auto s1s = __builtin_amdgcn_permlane32_swap(a1, b1, false, false);
          u32x4 fw = {(unsigned)s0s[0], (unsigned)s1s[0], (unsigned)s0s[1],
                      (unsigned)s1s[1]};
          F2 = __builtin_bit_cast(s16x8, fw);
          unsigned a2 = cvtpk(p1[8], p1[9]), b2 = cvtpk(p1[12], p1[13]);
          unsigned a3 = cvtpk(p1[10], p1[11]), b3 = cvtpk(p1[14], p1[15]);
          auto s2s = __builtin_amdgcn_permlane32_swap(a2, b2, false, false);
          auto s3s = __builtin_amdgcn_permlane32_swap(a3, b3, false, false);
          u32x4 fw2 = {(unsigned)s2s[0], (unsigned)s3s[0], (unsigned)s2s[1],
                       (unsigned)s3s[1]};
          F3 = __builtin_bit_cast(s16x8, fw2);
        }
        // --- all PV MFMAs, alternating accumulators (dep distance 2) ---
        // V chunk for fragment kk of this batch: off16[4*bs + kk]
        __builtin_amdgcn_s_setprio(1);
#pragma unroll
        for (int dn = 0; dn < 2; ++dn) {
          s16x8 vf = ld8(&Vb[(dn * 32 + l31) * 128 + off16[4 * bs + 0]]);
          oacc[dn] = MFMA32(F0, vf, oacc[dn]);
        }
#pragma unroll
        for (int dn = 0; dn < 2; ++dn) {
          s16x8 vf = ld8(&Vb[(dn * 32 + l31) * 128 + off16[4 * bs + 1]]);
          oacc[dn] = MFMA32(F1, vf, oacc[dn]);
        }
        if (dob) {
#pragma unroll
          for (int dn = 0; dn < 2; ++dn) {
            s16x8 vf = ld8(&Vb[(dn * 32 + l31) * 128 + off16[4 * bs + 2]]);
            oacc[dn] = MFMA32(F2, vf, oacc[dn]);
          }
#pragma unroll
          for (int dn = 0; dn < 2; ++dn) {
            s16x8 vf = ld8(&Vb[(dn * 32 + l31) * 128 + off16[4 * bs + 3]]);
            oacc[dn] = MFMA32(F3, vf, oacc[dn]);
          }
        }
        __builtin_amdgcn_s_setprio(0);
      }
    }

    // epilogue: l split across hi halves -> one shfl_xor(32), broadcast 1/l
    // through wave-private LDS, scale + store O
    {
      float ltot = lacc + __shfl_xor(lacc, 32);
      if (lane < 32) Lred[w * 32 + l31] = 1.f / ltot;
      f32x4 lv[4];
#pragma unroll
      for (int g = 0; g < 4; ++g)
        lv[g] = *(const f32x4*)&Lred[w * 32 + 8 * g + 4 * hi];
#pragma unroll
      for (int dn = 0; dn < 2; ++dn)
#pragma unroll
        for (int g = 0; g < 4; ++g)
#pragma unroll
          for (int j = 0; j < 4; ++j) {
            int s = rbase + 8 * g + 4 * hi + j;
            O[((size_t)(b * 2048 + s)) * 2048 + h * 64 + dn * 32 + l31] =
                f2bf(oacc[dn][4 * g + j] * lv[g][j]);
          }
    }
  }
}

// ---------------- launch ----------------
extern "C" void kernel_launch(void* const* d_in, const int* in_sizes, int n_in,
                              void* d_out, int out_size, void* d_ws,
                              size_t ws_size, hipStream_t stream) {
  const float* X = (const float*)d_in[0];
  const float* cosp = (const float*)d_in[1];
  const float* sinp = (const float*)d_in[2];
  const float* Wq = (const float*)d_in[4];
  const float* Wk = (const float*)d_in[5];
  const float* Wv = (const float*)d_in[6];
  const float* Wo = (const float*)d_in[7];
  float* out = (float*)d_out;

  u16* Xb = (u16*)d_ws;       // 8,388,608
  u16* Wqkv = Xb + 8388608;   // 3072x2048 (Wq|Wk|Wv rows)
  u16* Wob = Wqkv + 6291456;  // 4,194,304
  u16* Qr = Wob + 4194304;    // [2][32][2048][64]  (pre-scaled)
  u16* Kr = Qr + 8388608;     // [2][8][2048][64]
  u16* Vt = Kr + 2097152;     // [2][8][64][2048]
  u16* Ob = Vt + 2097152;     // [2][2048][2048]

  cvt_all<<<18432, 256, 0, stream>>>(X, Wq, Wk, Wv, Wo, Xb);

  gemm_nt<EPI_QKV><<<dim3(24, 32), 256, 0, stream>>>(
      Xb, Wqkv, cosp, sinp, Qr, Kr, Vt, nullptr, 2048);

  attn<<<dim3(8, 64), 256, 0, stream>>>(Qr, Kr, Vt, Ob);

  gemm_nt<EPI_OUT><<<dim3(16, 32), 256, 0, stream>>>(
      Ob, Wob, nullptr, nullptr, nullptr, nullptr, nullptr, out, 2048);
}

// Round 8
// 302.034 us; speedup vs baseline: 1.1889x; 1.0224x over previous
//
#include <hip/hip_runtime.h>

typedef unsigned short u16;
typedef __attribute__((ext_vector_type(8))) short s16x8;
typedef __attribute__((ext_vector_type(4))) float f32x4;
typedef __attribute__((ext_vector_type(16))) float f32x16;
typedef __attribute__((ext_vector_type(4))) unsigned short u16x4;
typedef __attribute__((ext_vector_type(4))) unsigned int u32x4;

#define MFMA16(a, b, c) __builtin_amdgcn_mfma_f32_16x16x32_bf16(a, b, c, 0, 0, 0)
#define MFMA32(a, b, c) __builtin_amdgcn_mfma_f32_32x32x16_bf16(a, b, c, 0, 0, 0)

__device__ __forceinline__ u16 f2bf(float f) {
  unsigned u = __builtin_bit_cast(unsigned, f);
  u += 0x7fffu + ((u >> 16) & 1u);  // RNE
  return (u16)(u >> 16);
}

__device__ __forceinline__ void async16(const void* g, void* l) {
  __builtin_amdgcn_global_load_lds(
      (const __attribute__((address_space(1))) void*)g,
      (__attribute__((address_space(3))) void*)l, 16, 0, 0);
}

__device__ __forceinline__ s16x8 ld8(const u16* p) { return *(const s16x8*)p; }

// packed f32x2 -> bf16x2 (RNE); no builtin on gfx950, inline asm per T12
__device__ __forceinline__ unsigned cvtpk(float lo, float hi) {
  unsigned r;
  asm("v_cvt_pk_bf16_f32 %0, %1, %2" : "=v"(r) : "v"(lo), "v"(hi));
  return r;
}

// log2(e) / sqrt(64) folded into Q at projection time
#define PRE 0.18033688011112042f

// ---------------- fused fp32 -> bf16 cast of all 5 tensors ----------------
__global__ __launch_bounds__(256) void cvt_all(
    const float* __restrict__ X, const float* __restrict__ Wq,
    const float* __restrict__ Wk, const float* __restrict__ Wv,
    const float* __restrict__ Wo, u16* __restrict__ out) {
  long e = (long)(blockIdx.x * 256 + threadIdx.x) * 4;
  const float* src;
  if (e < 8388608L) src = X + e;
  else if (e < 12582912L) src = Wq + (e - 8388608L);
  else if (e < 13631488L) src = Wk + (e - 12582912L);
  else if (e < 14680064L) src = Wv + (e - 13631488L);
  else src = Wo + (e - 14680064L);
  float4 v = *(const float4*)src;
  u16x4 o = {f2bf(v.x), f2bf(v.y), f2bf(v.z), f2bf(v.w)};
  *(u16x4*)(out + e) = o;
}

// ---------------- NT GEMM: C[m,n] = sum_k A[m,k]*B[n,k] ----------------
// 128x128 tile, BK=32, double-buffered LDS, ONE barrier per K-iter. Tiles
// stored as 64 double-rows x 8 XOR-swizzled 16B chunks (conflict-free).
// [round-1 verified @78.5us QKV, 656 TF. Negative results on this kernel:
//  counted-vmcnt graft (r3), 256^2 tiles (r3: grid underfill), Q/K epilogue
//  LDS-transpose (r6: scattered 2B async stores were FREE at 17% HBM; the
//  LDS round-trip cost 8us). Keep the scattered-store epilogue.]
enum { EPI_QKV = 0, EPI_OUT = 1 };

template <int EPI>
__global__ __launch_bounds__(256) void gemm_nt(
    const u16* __restrict__ A, const u16* __restrict__ Bm,
    const float* __restrict__ cosp, const float* __restrict__ sinp,
    u16* __restrict__ Qo, u16* __restrict__ Ko, u16* __restrict__ Vo,
    float* __restrict__ Co, int K) {
  // [2 buffers][A: 4096 u16 | B: 4096 u16] = 32 KB; epilogue reuses all 32 KB
  __shared__ u16 SM[16384];
  const int t = threadIdx.x;
  const int lane = t & 63;
  const int w = t >> 6, wm = w >> 1, wn = w & 1;
  const int quad = lane >> 4, c16 = lane & 15;
  const int m0 = blockIdx.y * 128, n0 = blockIdx.x * 128;

  f32x4 acc[4][4];
  const f32x4 zero = {0.f, 0.f, 0.f, 0.f};
#pragma unroll
  for (int i = 0; i < 4; ++i)
#pragma unroll
    for (int j = 0; j < 4; ++j) acc[i][j] = zero;

  // staging: chunk c (16B) of a 128x32 tile holds global
  //   double-row dr=c>>3, k8=(c&7)^(dr&7) -> (row 2dr+(k8>>2), colchunk k8&3)
  const u16* gA[2];
  const u16* gB[2];
  int lof[2];
#pragma unroll
  for (int p = 0; p < 2; ++p) {
    int c = t + p * 256;
    int dr = c >> 3, k8 = (c & 7) ^ (dr & 7);
    int row = 2 * dr + (k8 >> 2), col = (k8 & 3) * 8;
    gA[p] = A + (size_t)(m0 + row) * K + col;
    gB[p] = Bm + (size_t)(n0 + row) * K + col;
    lof[p] = c * 8;  // u16 index within a buffer half
  }

  // fragment LDS offsets (loop-invariant; toggle buffer by +8192)
  int aoff[4], boff[4];
#pragma unroll
  for (int i = 0; i < 4; ++i) {
    int rowA = wm * 64 + i * 16 + c16;
    int drA = rowA >> 1;
    int chA = (((rowA & 1) << 2) | quad) ^ (drA & 7);
    aoff[i] = drA * 64 + chA * 8;
    int rowB = wn * 64 + i * 16 + c16;
    int drB = rowB >> 1;
    int chB = (((rowB & 1) << 2) | quad) ^ (drB & 7);
    boff[i] = 4096 + drB * 64 + chB * 8;
  }

  // prologue: stage buffer 0 with k-slab 0
#pragma unroll
  for (int p = 0; p < 2; ++p) {
    async16(gA[p], &SM[lof[p]]);
    async16(gB[p], &SM[4096 + lof[p]]);
  }

  const int niter = K >> 5;
  for (int kt = 0; kt < niter; ++kt) {
    const int cb = (kt & 1) * 8192;
    __syncthreads();  // drains vmcnt: buf[cur] staged; prev reads of buf[nxt] done
    if (kt + 1 < niter) {
      const int nb = 8192 - cb;
#pragma unroll
      for (int p = 0; p < 2; ++p) {
        gA[p] += 32;
        gB[p] += 32;
        async16(gA[p], &SM[nb + lof[p]]);
        async16(gB[p], &SM[nb + 4096 + lof[p]]);
      }
    }
    s16x8 af[4], bfr[4];
#pragma unroll
    for (int i = 0; i < 4; ++i) af[i] = ld8(&SM[cb + aoff[i]]);
#pragma unroll
    for (int j = 0; j < 4; ++j) bfr[j] = ld8(&SM[cb + boff[j]]);
#pragma unroll
    for (int i = 0; i < 4; ++i)
#pragma unroll
      for (int j = 0; j < 4; ++j) acc[i][j] = MFMA16(af[i], bfr[j], acc[i][j]);
  }

  if (EPI == EPI_OUT) {
#pragma unroll
    for (int i = 0; i < 4; ++i)
#pragma unroll
      for (int r = 0; r < 4; ++r) {
        int m = m0 + wm * 64 + i * 16 + quad * 4 + r;
        float* dst = Co + (size_t)m * 2048 + n0 + wn * 64 + c16;
#pragma unroll
        for (int j = 0; j < 4; ++j) dst[j * 16] = acc[i][j][r];
      }
  } else if (n0 >= 2560) {
    // V zone: transpose via LDS -> coalesced 16B stores of V^T [B][8][64][S]
    __syncthreads();  // all K-loop LDS reads done before overwrite
#pragma unroll
    for (int i = 0; i < 4; ++i)
#pragma unroll
      for (int r = 0; r < 4; ++r) {
        int sl = wm * 64 + i * 16 + quad * 4 + r;
#pragma unroll
        for (int j = 0; j < 4; ++j) {
          int dl = wn * 64 + j * 16 + c16;
          SM[dl * 128 + (((sl >> 3) ^ (dl & 15)) * 8) + (sl & 7)] =
              f2bf(acc[i][j][r]);
        }
      }
    __syncthreads();
    int bb = m0 >> 11, m0s = m0 & 2047;
#pragma unroll
    for (int p = 0; p < 8; ++p) {
      int q = p * 256 + t;
      int dl = q >> 4, k = q & 15;
      s16x8 vrow = ld8(&SM[dl * 128 + ((k ^ (dl & 15)) * 8)]);
      int nab = n0 + dl;
      int kvh = (nab - 2560) >> 6, dh = nab & 63;
      *(s16x8*)(Vo + ((size_t)(bb * 8 + kvh) * 64 + dh) * 2048 + m0s + k * 8) =
          vrow;
    }
  } else {
    const int nbase = n0 + wn * 64;
#pragma unroll
    for (int i = 0; i < 4; ++i)
#pragma unroll
      for (int r = 0; r < 4; ++r) {
        int m = m0 + wm * 64 + i * 16 + quad * 4 + r;
        int b = m >> 11, s = m & 2047;
        if (nbase < 2048) {  // Q zone: rope + prescale, store [B][32][S][64]
          int h = nbase >> 6;
          size_t base = ((size_t)(b * 32 + h) * 2048 + s) * 64;
#pragma unroll
          for (int j = 0; j < 2; ++j) {
            int d = j * 16 + c16;
            float v1 = acc[i][j][r], v2 = acc[i][j + 2][r];
            float c1 = cosp[m * 64 + d], s1 = sinp[m * 64 + d];
            float c2 = cosp[m * 64 + d + 32], s2 = sinp[m * 64 + d + 32];
            Qo[base + d] = f2bf((v1 * c1 - v2 * s1) * PRE);
            Qo[base + d + 32] = f2bf((v2 * c2 + v1 * s2) * PRE);
          }
        } else {  // K zone: rope, store [B][8][S][64]
          int h = (nbase - 2048) >> 6;
          size_t base = ((size_t)(b * 8 + h) * 2048 + s) * 64;
#pragma unroll
          for (int j = 0; j < 2; ++j) {
            int d = j * 16 + c16;
            float v1 = acc[i][j][r], v2 = acc[i][j + 2][r];
            float c1 = cosp[m * 64 + d], s1 = sinp[m * 64 + d];
            float c2 = cosp[m * 64 + d + 32], s2 = sinp[m * 64 + d + 32];
            Ko[base + d] = f2bf(v1 * c1 - v2 * s1);
            Ko[base + d + 32] = f2bf(v2 * c2 + v1 * s2);
          }
        }
      }
  }
}

// ---------------- flash attention (causal, GQA) ----------------
// Round-8: BQ 128 -> 256 (8 waves, 512 threads). grid (4 qt-pairs, 64 b*h)
// = 256 blocks, pairs {x, 7-x} = exactly 18 k-iters each (balanced).
// WHY: attn is staging-bound, not pipe-bound. At BQ=128, 512 blocks each
// re-stage their full K/V prefix: 278 MB moved L3->LDS for 16.8 MB unique
// (33x refetch). BQ=256 halves that (147 MB) and doubles compute per staged
// byte, so each drain is smaller AND better covered. Per-wave inner math,
// barrier pattern, swizzles, epilogue are unchanged (parameter change only).
// KVBLK=128 (r7). LDS 65KB -> 1 block/CU x 8 waves = same 8 waves/CU.
// Swapped-operand 32x32x16 MFMA (S^T = mfma(K,Q)) + in-register P via T12.
// Fixed-m (m=0) online softmax; l-reduction deferred to epilogue.
__global__ __launch_bounds__(512) void attn(const u16* __restrict__ Q,
                                            const u16* __restrict__ Kg,
                                            const u16* __restrict__ Vg,
                                            u16* __restrict__ O) {
  __shared__ u16 Ks[2][8192];   // [buf][128 keys][64 d], XOR-swizzled chunks
  __shared__ u16 Vs[2][8192];   // [buf][64 d][128 keys] (V^T), 16-chunk swz
  __shared__ float Lred[256];   // per-wave 1/l broadcast (32 floats/wave)
  const int t = threadIdx.x;    // 0..511
  const int lane = t & 63;
  const int w = t >> 6;         // 0..7
  const int l31 = lane & 31, hi = lane >> 5;
  const int bh = blockIdx.y;
  const int b = bh >> 5, h = bh & 31;
  const int kvh = h >> 2;  // G = 4

  const u16* Qbase = Q + ((size_t)(b * 32 + h) * 2048) * 64;
  const u16* Kbase = Kg + ((size_t)(b * 8 + kvh) * 2048) * 64;
  const u16* Vbase = Vg + ((size_t)(b * 8 + kvh) * 64) * 2048;

  // staging precompute: thread covers 2 K-chunks + 2 V-chunks per tile
  int kro[2], kco[2], vro[2], vco[2];
#pragma unroll
  for (int p = 0; p < 2; ++p) {
    int c = t + p * 512;
    kro[p] = c >> 3;
    kco[p] = ((c & 7) ^ (kro[p] & 7)) * 8;
    vro[p] = c >> 4;
    vco[p] = ((c & 15) ^ (vro[p] & 15)) * 8;
  }

  // read-side swizzled chunk offsets
  int off8[4];   // K: chunk 2dc+hi of 8, rows%8-swizzled
#pragma unroll
  for (int c = 0; c < 4; ++c) off8[c] = ((2 * c + hi) ^ (l31 & 7)) * 8;
  int off16[8];  // V: chunk 2kk+hi of 16, rows%16-swizzled
#pragma unroll
  for (int c = 0; c < 8; ++c) off16[c] = ((2 * c + hi) ^ (l31 & 15)) * 8;
  const int rbB = l31 * 64;

  for (int ph = 0; ph < 2; ++ph) {
    const int qt = ph ? 7 - blockIdx.x : blockIdx.x;
    const int q0 = qt * 256;
    const int rbase = q0 + w * 32;
    const int qrow = rbase + l31;  // this lane's q-row (S^T column)

    s16x8 qf[4];
#pragma unroll
    for (int dc = 0; dc < 4; ++dc)
      qf[dc] = ld8(Qbase + (size_t)qrow * 64 + dc * 16 + hi * 8);

    f32x16 oacc[2];
#pragma unroll
    for (int dn = 0; dn < 2; ++dn)
#pragma unroll
      for (int r = 0; r < 16; ++r) oacc[dn][r] = 0.f;
    float lacc = 0.f;

    const int nkt = 2 * qt + 2;  // 128-key tiles covering q0+256 rows

    __syncthreads();  // previous phase's LDS reads done before restaging buf0
#pragma unroll
    for (int p = 0; p < 2; ++p) {
      async16(Kbase + (size_t)kro[p] * 64 + kco[p], &Ks[0][(t + p * 512) * 8]);
      async16(Vbase + (size_t)vro[p] * 2048 + vco[p],
              &Vs[0][(t + p * 512) * 8]);
    }

    for (int kt = 0; kt < nkt; ++kt) {
      const int cur = kt & 1;
      __syncthreads();  // buf[cur] staged; prev reads of buf[1-cur] done
      if (kt + 1 < nkt) {
        const int nxt = 1 - cur;
        const u16* kg = Kbase + (size_t)(kt + 1) * 8192;
        const u16* vg = Vbase + (kt + 1) * 128;
#pragma unroll
        for (int p = 0; p < 2; ++p) {
          async16(kg + (size_t)kro[p] * 64 + kco[p],
                  &Ks[nxt][(t + p * 512) * 8]);
          async16(vg + (size_t)vro[p] * 2048 + vco[p],
                  &Vs[nxt][(t + p * 512) * 8]);
        }
      }
      const u16* Kb = Ks[cur];
      const u16* Vb = Vs[cur];

#pragma unroll
      for (int bs = 0; bs < 2; ++bs) {
        const int kb0 = kt * 128 + bs * 64;
        if (kb0 > rbase + 31) continue;  // fully-masked 64-key batch
        const bool dob = (kb0 + 32 <= rbase + 31);
        // --- both QK^T chains issued back-to-back (independent accs) ---
        f32x16 s0, s1;
#pragma unroll
        for (int r = 0; r < 16; ++r) s0[r] = 0.f;
#pragma unroll
        for (int r = 0; r < 16; ++r) s1[r] = 0.f;
        __builtin_amdgcn_s_setprio(1);
#pragma unroll
        for (int dc = 0; dc < 4; ++dc) {
          s16x8 kf = ld8(&Kb[(2 * bs) * 2048 + rbB + off8[dc]]);
          s0 = MFMA32(kf, qf[dc], s0);
        }
        if (dob) {
#pragma unroll
          for (int dc = 0; dc < 4; ++dc) {
            s16x8 kf = ld8(&Kb[(2 * bs + 1) * 2048 + rbB + off8[dc]]);
            s1 = MFMA32(kf, qf[dc], s1);
          }
        }
        __builtin_amdgcn_s_setprio(0);
        // --- causal masks (diagonal tiles only; wave-uniform branches) ---
        if (kb0 + 31 > rbase) {
          const int kb = kb0 + 4 * hi;
#pragma unroll
          for (int r = 0; r < 16; ++r)
            if (kb + (r & 3) + 8 * (r >> 2) > qrow) s0[r] = -1e30f;
        }
        if (dob && kb0 + 63 > rbase) {
          const int kb = kb0 + 32 + 4 * hi;
#pragma unroll
          for (int r = 0; r < 16; ++r)
            if (kb + (r & 3) + 8 * (r >> 2) > qrow) s1[r] = -1e30f;
        }
        // --- independent exp2 ---
        float p0[16], p1[16];
#pragma unroll
        for (int r = 0; r < 16; ++r) p0[r] = __builtin_amdgcn_exp2f(s0[r]);
        if (dob) {
#pragma unroll
          for (int r = 0; r < 16; ++r) p1[r] = __builtin_amdgcn_exp2f(s1[r]);
        }
        // --- l accumulation (balanced trees) ---
        {
          float e0 = p0[0] + p0[1], e1 = p0[2] + p0[3], e2 = p0[4] + p0[5],
                e3 = p0[6] + p0[7], e4 = p0[8] + p0[9], e5 = p0[10] + p0[11],
                e6 = p0[12] + p0[13], e7 = p0[14] + p0[15];
          lacc += ((e0 + e1) + (e2 + e3)) + ((e4 + e5) + (e6 + e7));
        }
        if (dob) {
          float e0 = p1[0] + p1[1], e1 = p1[2] + p1[3], e2 = p1[4] + p1[5],
                e3 = p1[6] + p1[7], e4 = p1[8] + p1[9], e5 = p1[10] + p1[11],
                e6 = p1[12] + p1[13], e7 = p1[14] + p1[15];
          lacc += ((e0 + e1) + (e2 + e3)) + ((e4 + e5) + (e6 + e7));
        }
        // --- T12 fragment builds for all live kk ---
        s16x8 F0, F1, F2, F3;
        {
          unsigned a0 = cvtpk(p0[0], p0[1]), b0 = cvtpk(p0[4], p0[5]);
          unsigned a1 = cvtpk(p0[2], p0[3]), b1 = cvtpk(p0[6], p0[7]);
          auto s0s = __builtin_amdgcn_permlane32_swap(a0, b0, false, false);
          auto s1s = __builtin_amdgcn_permlane32_swap(a1, b1, false, false);
          u32x4 fw = {(unsigned)s0s[0], (unsigned)s1s[0], (unsigned)s0s[1],
                      (unsigned)s1s[1]};
          F0 = __builtin_bit_cast(s16x8, fw);
          unsigned a2 = cvtpk(p0[8], p0[9]), b2 = cvtpk(p0[12], p0[13]);
          unsigned a3 = cvtpk(p0[10], p0[11]), b3 = cvtpk(p0[14], p0[15]);
          auto s2s = __builtin_amdgcn_permlane32_swap(a2, b2, false, false);
          auto s3s = __builtin_amdgcn_permlane32_swap(a3, b3, false, false);
          u32x4 fw2 = {(unsigned)s2s[0], (unsigned)s3s[0], (unsigned)s2s[1],
                       (unsigned)s3s[1]};
          F1 = __builtin_bit_cast(s16x8, fw2);
        }
        if (dob) {
          unsigned a0 = cvtpk(p1[0], p1[1]), b0 = cvtpk(p1[4], p1[5]);
          unsigned a1 = cvtpk(p1[2], p1[3]), b1 = cvtpk(p1[6], p1[7]);
          auto s0s = __builtin_amdgcn_permlane32_swap(a0, b0, false, false);
          auto s1s = __builtin_amdgcn_permlane32_swap(a1, b1, false, false);
          u32x4 fw = {(unsigned)s0s[0], (unsigned)s1s[0], (unsigned)s0s[1],
                      (unsigned)s1s[1]};
          F2 = __builtin_bit_cast(s16x8, fw);
          unsigned a2 = cvtpk(p1[8], p1[9]), b2 = cvtpk(p1[12], p1[13]);
          unsigned a3 = cvtpk(p1[10], p1[11]), b3 = cvtpk(p1[14], p1[15]);
          auto s2s = __builtin_amdgcn_permlane32_swap(a2, b2, false, false);
          auto s3s = __builtin_amdgcn_permlane32_swap(a3, b3, false, false);
          u32x4 fw2 = {(unsigned)s2s[0], (unsigned)s3s[0], (unsigned)s2s[1],
                       (unsigned)s3s[1]};
          F3 = __builtin_bit_cast(s16x8, fw2);
        }
        // --- all PV MFMAs, alternating accumulators (dep distance 2) ---
        // V chunk for fragment kk of this batch: off16[4*bs + kk]
        __builtin_amdgcn_s_setprio(1);
#pragma unroll
        for (int dn = 0; dn < 2; ++dn) {
          s16x8 vf = ld8(&Vb[(dn * 32 + l31) * 128 + off16[4 * bs + 0]]);
          oacc[dn] = MFMA32(F0, vf, oacc[dn]);
        }
#pragma unroll
        for (int dn = 0; dn < 2; ++dn) {
          s16x8 vf = ld8(&Vb[(dn * 32 + l31) * 128 + off16[4 * bs + 1]]);
          oacc[dn] = MFMA32(F1, vf, oacc[dn]);
        }
        if (dob) {
#pragma unroll
          for (int dn = 0; dn < 2; ++dn) {
            s16x8 vf = ld8(&Vb[(dn * 32 + l31) * 128 + off16[4 * bs + 2]]);
            oacc[dn] = MFMA32(F2, vf, oacc[dn]);
          }
#pragma unroll
          for (int dn = 0; dn < 2; ++dn) {
            s16x8 vf = ld8(&Vb[(dn * 32 + l31) * 128 + off16[4 * bs + 3]]);
            oacc[dn] = MFMA32(F3, vf, oacc[dn]);
          }
        }
        __builtin_amdgcn_s_setprio(0);
      }
    }

    // epilogue: l split across hi halves -> one shfl_xor(32), broadcast 1/l
    // through wave-private LDS, scale + store O
    {
      float ltot = lacc + __shfl_xor(lacc, 32);
      if (lane < 32) Lred[w * 32 + l31] = 1.f / ltot;
      f32x4 lv[4];
#pragma unroll
      for (int g = 0; g < 4; ++g)
        lv[g] = *(const f32x4*)&Lred[w * 32 + 8 * g + 4 * hi];
#pragma unroll
      for (int dn = 0; dn < 2; ++dn)
#pragma unroll
        for (int g = 0; g < 4; ++g)
#pragma unroll
          for (int j = 0; j < 4; ++j) {
            int s = rbase + 8 * g + 4 * hi + j;
            O[((size_t)(b * 2048 + s)) * 2048 + h * 64 + dn * 32 + l31] =
                f2bf(oacc[dn][4 * g + j] * lv[g][j]);
          }
    }
  }
}

// ---------------- launch ----------------
extern "C" void kernel_launch(void* const* d_in, const int* in_sizes, int n_in,
                              void* d_out, int out_size, void* d_ws,
                              size_t ws_size, hipStream_t stream) {
  const float* X = (const float*)d_in[0];
  const float* cosp = (const float*)d_in[1];
  const float* sinp = (const float*)d_in[2];
  const float* Wq = (const float*)d_in[4];
  const float* Wk = (const float*)d_in[5];
  const float* Wv = (const float*)d_in[6];
  const float* Wo = (const float*)d_in[7];
  float* out = (float*)d_out;

  u16* Xb = (u16*)d_ws;       // 8,388,608
  u16* Wqkv = Xb + 8388608;   // 3072x2048 (Wq|Wk|Wv rows)
  u16* Wob = Wqkv + 6291456;  // 4,194,304
  u16* Qr = Wob + 4194304;    // [2][32][2048][64]  (pre-scaled)
  u16* Kr = Qr + 8388608;     // [2][8][2048][64]
  u16* Vt = Kr + 2097152;     // [2][8][64][2048]
  u16* Ob = Vt + 2097152;     // [2][2048][2048]

  cvt_all<<<18432, 256, 0, stream>>>(X, Wq, Wk, Wv, Wo, Xb);

  gemm_nt<EPI_QKV><<<dim3(24, 32), 256, 0, stream>>>(
      Xb, Wqkv, cosp, sinp, Qr, Kr, Vt, nullptr, 2048);

  attn<<<dim3(4, 64), 512, 0, stream>>>(Qr, Kr, Vt, Ob);

  gemm_nt<EPI_OUT><<<dim3(16, 32), 256, 0, stream>>>(
      Ob, Wob, nullptr, nullptr, nullptr, nullptr, nullptr, out, 2048);
}

// Round 9
// 299.479 us; speedup vs baseline: 1.1991x; 1.0085x over previous
//
#include <hip/hip_runtime.h>

typedef unsigned short u16;
typedef __attribute__((ext_vector_type(8))) short s16x8;
typedef __attribute__((ext_vector_type(4))) float f32x4;
typedef __attribute__((ext_vector_type(16))) float f32x16;
typedef __attribute__((ext_vector_type(4))) unsigned short u16x4;
typedef __attribute__((ext_vector_type(4))) unsigned int u32x4;

#define MFMA16(a, b, c) __builtin_amdgcn_mfma_f32_16x16x32_bf16(a, b, c, 0, 0, 0)
#define MFMA32(a, b, c) __builtin_amdgcn_mfma_f32_32x32x16_bf16(a, b, c, 0, 0, 0)

__device__ __forceinline__ u16 f2bf(float f) {
  unsigned u = __builtin_bit_cast(unsigned, f);
  u += 0x7fffu + ((u >> 16) & 1u);  // RNE
  return (u16)(u >> 16);
}

__device__ __forceinline__ void async16(const void* g, void* l) {
  __builtin_amdgcn_global_load_lds(
      (const __attribute__((address_space(1))) void*)g,
      (__attribute__((address_space(3))) void*)l, 16, 0, 0);
}

__device__ __forceinline__ s16x8 ld8(const u16* p) { return *(const s16x8*)p; }

// packed f32x2 -> bf16x2 (RNE); no builtin on gfx950, inline asm per T12
__device__ __forceinline__ unsigned cvtpk(float lo, float hi) {
  unsigned r;
  asm("v_cvt_pk_bf16_f32 %0, %1, %2" : "=v"(r) : "v"(lo), "v"(hi));
  return r;
}

// log2(e) / sqrt(64) folded into Q at projection time
#define PRE 0.18033688011112042f

// ---------------- fused fp32 -> bf16 cast of all 5 tensors ----------------
__global__ __launch_bounds__(256) void cvt_all(
    const float* __restrict__ X, const float* __restrict__ Wq,
    const float* __restrict__ Wk, const float* __restrict__ Wv,
    const float* __restrict__ Wo, u16* __restrict__ out) {
  long e = (long)(blockIdx.x * 256 + threadIdx.x) * 4;
  const float* src;
  if (e < 8388608L) src = X + e;
  else if (e < 12582912L) src = Wq + (e - 8388608L);
  else if (e < 13631488L) src = Wk + (e - 12582912L);
  else if (e < 14680064L) src = Wv + (e - 13631488L);
  else src = Wo + (e - 14680064L);
  float4 v = *(const float4*)src;
  u16x4 o = {f2bf(v.x), f2bf(v.y), f2bf(v.z), f2bf(v.w)};
  *(u16x4*)(out + e) = o;
}

// ---------------- NT GEMM: C[m,n] = sum_k A[m,k]*B[n,k] ----------------
// 128x128 tile, BK=32, double-buffered LDS, ONE barrier per K-iter. Tiles
// stored as 64 double-rows x 8 XOR-swizzled 16B chunks (conflict-free).
// [round-1 verified @78.5us QKV, 656 TF. Negative results: counted-vmcnt
//  graft (r3), 256^2 tiles (r3: underfill), Q/K epilogue LDS-transpose (r6).]
//
// Round-9: T1 XCD-chunked block swizzle. Per-round arithmetic (r8) showed
// the K-loop is drain-LATENCY bound (OUT: 735 cyc/iter-slot vs 240 compute)
// with 80MB L2-miss traffic per dispatch from panel re-reads scattered
// across XCDs. Chunked remap gives each XCD a contiguous run of work ids ->
// its A-panels become L2-resident (read 16-24x from L2 instead of L3/HBM),
// shortening every barrier drain. Bijective: all grids %8 == 0.
enum { EPI_QKV = 0, EPI_OUT = 1 };

template <int EPI>
__global__ __launch_bounds__(256) void gemm_nt(
    const u16* __restrict__ A, const u16* __restrict__ Bm,
    const float* __restrict__ cosp, const float* __restrict__ sinp,
    u16* __restrict__ Qo, u16* __restrict__ Ko, u16* __restrict__ Vo,
    float* __restrict__ Co, int K) {
  // [2 buffers][A: 4096 u16 | B: 4096 u16] = 32 KB; epilogue reuses all 32 KB
  __shared__ u16 SM[16384];
  const int t = threadIdx.x;
  const int lane = t & 63;
  const int w = t >> 6, wm = w >> 1, wn = w & 1;
  const int quad = lane >> 4, c16 = lane & 15;
  // T1 XCD-chunked swizzle (hw id round-robins XCDs; give each XCD a
  // contiguous chunk of work ids so shared panels stay in its L2)
  const int nxb = gridDim.x;
  const int id = blockIdx.y * nxb + blockIdx.x;
  const int cpx = (nxb * gridDim.y) >> 3;
  const int work = (id & 7) * cpx + (id >> 3);
  const int m0 = (work / nxb) * 128, n0 = (work % nxb) * 128;

  f32x4 acc[4][4];
  const f32x4 zero = {0.f, 0.f, 0.f, 0.f};
#pragma unroll
  for (int i = 0; i < 4; ++i)
#pragma unroll
    for (int j = 0; j < 4; ++j) acc[i][j] = zero;

  // staging: chunk c (16B) of a 128x32 tile holds global
  //   double-row dr=c>>3, k8=(c&7)^(dr&7) -> (row 2dr+(k8>>2), colchunk k8&3)
  const u16* gA[2];
  const u16* gB[2];
  int lof[2];
#pragma unroll
  for (int p = 0; p < 2; ++p) {
    int c = t + p * 256;
    int dr = c >> 3, k8 = (c & 7) ^ (dr & 7);
    int row = 2 * dr + (k8 >> 2), col = (k8 & 3) * 8;
    gA[p] = A + (size_t)(m0 + row) * K + col;
    gB[p] = Bm + (size_t)(n0 + row) * K + col;
    lof[p] = c * 8;  // u16 index within a buffer half
  }

  // fragment LDS offsets (loop-invariant; toggle buffer by +8192)
  int aoff[4], boff[4];
#pragma unroll
  for (int i = 0; i < 4; ++i) {
    int rowA = wm * 64 + i * 16 + c16;
    int drA = rowA >> 1;
    int chA = (((rowA & 1) << 2) | quad) ^ (drA & 7);
    aoff[i] = drA * 64 + chA * 8;
    int rowB = wn * 64 + i * 16 + c16;
    int drB = rowB >> 1;
    int chB = (((rowB & 1) << 2) | quad) ^ (drB & 7);
    boff[i] = 4096 + drB * 64 + chB * 8;
  }

  // prologue: stage buffer 0 with k-slab 0
#pragma unroll
  for (int p = 0; p < 2; ++p) {
    async16(gA[p], &SM[lof[p]]);
    async16(gB[p], &SM[4096 + lof[p]]);
  }

  const int niter = K >> 5;
  for (int kt = 0; kt < niter; ++kt) {
    const int cb = (kt & 1) * 8192;
    __syncthreads();  // drains vmcnt: buf[cur] staged; prev reads of buf[nxt] done
    if (kt + 1 < niter) {
      const int nb = 8192 - cb;
#pragma unroll
      for (int p = 0; p < 2; ++p) {
        gA[p] += 32;
        gB[p] += 32;
        async16(gA[p], &SM[nb + lof[p]]);
        async16(gB[p], &SM[nb + 4096 + lof[p]]);
      }
    }
    s16x8 af[4], bfr[4];
#pragma unroll
    for (int i = 0; i < 4; ++i) af[i] = ld8(&SM[cb + aoff[i]]);
#pragma unroll
    for (int j = 0; j < 4; ++j) bfr[j] = ld8(&SM[cb + boff[j]]);
#pragma unroll
    for (int i = 0; i < 4; ++i)
#pragma unroll
      for (int j = 0; j < 4; ++j) acc[i][j] = MFMA16(af[i], bfr[j], acc[i][j]);
  }

  if (EPI == EPI_OUT) {
#pragma unroll
    for (int i = 0; i < 4; ++i)
#pragma unroll
      for (int r = 0; r < 4; ++r) {
        int m = m0 + wm * 64 + i * 16 + quad * 4 + r;
        float* dst = Co + (size_t)m * 2048 + n0 + wn * 64 + c16;
#pragma unroll
        for (int j = 0; j < 4; ++j) dst[j * 16] = acc[i][j][r];
      }
  } else if (n0 >= 2560) {
    // V zone: transpose via LDS -> coalesced 16B stores of V^T [B][8][64][S]
    __syncthreads();  // all K-loop LDS reads done before overwrite
#pragma unroll
    for (int i = 0; i < 4; ++i)
#pragma unroll
      for (int r = 0; r < 4; ++r) {
        int sl = wm * 64 + i * 16 + quad * 4 + r;
#pragma unroll
        for (int j = 0; j < 4; ++j) {
          int dl = wn * 64 + j * 16 + c16;
          SM[dl * 128 + (((sl >> 3) ^ (dl & 15)) * 8) + (sl & 7)] =
              f2bf(acc[i][j][r]);
        }
      }
    __syncthreads();
    int bb = m0 >> 11, m0s = m0 & 2047;
#pragma unroll
    for (int p = 0; p < 8; ++p) {
      int q = p * 256 + t;
      int dl = q >> 4, k = q & 15;
      s16x8 vrow = ld8(&SM[dl * 128 + ((k ^ (dl & 15)) * 8)]);
      int nab = n0 + dl;
      int kvh = (nab - 2560) >> 6, dh = nab & 63;
      *(s16x8*)(Vo + ((size_t)(bb * 8 + kvh) * 64 + dh) * 2048 + m0s + k * 8) =
          vrow;
    }
  } else {
    const int nbase = n0 + wn * 64;
#pragma unroll
    for (int i = 0; i < 4; ++i)
#pragma unroll
      for (int r = 0; r < 4; ++r) {
        int m = m0 + wm * 64 + i * 16 + quad * 4 + r;
        int b = m >> 11, s = m & 2047;
        if (nbase < 2048) {  // Q zone: rope + prescale, store [B][32][S][64]
          int h = nbase >> 6;
          size_t base = ((size_t)(b * 32 + h) * 2048 + s) * 64;
#pragma unroll
          for (int j = 0; j < 2; ++j) {
            int d = j * 16 + c16;
            float v1 = acc[i][j][r], v2 = acc[i][j + 2][r];
            float c1 = cosp[m * 64 + d], s1 = sinp[m * 64 + d];
            float c2 = cosp[m * 64 + d + 32], s2 = sinp[m * 64 + d + 32];
            Qo[base + d] = f2bf((v1 * c1 - v2 * s1) * PRE);
            Qo[base + d + 32] = f2bf((v2 * c2 + v1 * s2) * PRE);
          }
        } else {  // K zone: rope, store [B][8][S][64]
          int h = (nbase - 2048) >> 6;
          size_t base = ((size_t)(b * 8 + h) * 2048 + s) * 64;
#pragma unroll
          for (int j = 0; j < 2; ++j) {
            int d = j * 16 + c16;
            float v1 = acc[i][j][r], v2 = acc[i][j + 2][r];
            float c1 = cosp[m * 64 + d], s1 = sinp[m * 64 + d];
            float c2 = cosp[m * 64 + d + 32], s2 = sinp[m * 64 + d + 32];
            Ko[base + d] = f2bf(v1 * c1 - v2 * s1);
            Ko[base + d + 32] = f2bf(v2 * c2 + v1 * s2);
          }
        }
      }
  }
}

// ---------------- flash attention (causal, GQA) ----------------
// BQ=256 (8 waves, 512 threads), KVBLK=128. grid 256 blocks, pairs {x, 7-x}
// = exactly 18 k-iters each (balanced; r4 un-pairing regressed).
// Round-9: T1 XCD-chunked swizzle — the 4 q-blocks of one (b,h) share the
// whole K/V stream; chunking puts each XCD's 32 work ids on 8 bh = 2 kvh
// (1 MB K/V) -> L2-resident reuse instead of cross-XCD re-fetch.
// Swapped-operand 32x32x16 MFMA (S^T = mfma(K,Q)) + in-register P via T12.
// Fixed-m (m=0) online softmax; l-reduction deferred to epilogue.
__global__ __launch_bounds__(512) void attn(const u16* __restrict__ Q,
                                            const u16* __restrict__ Kg,
                                            const u16* __restrict__ Vg,
                                            u16* __restrict__ O) {
  __shared__ u16 Ks[2][8192];   // [buf][128 keys][64 d], XOR-swizzled chunks
  __shared__ u16 Vs[2][8192];   // [buf][64 d][128 keys] (V^T), 16-chunk swz
  __shared__ float Lred[256];   // per-wave 1/l broadcast (32 floats/wave)
  const int t = threadIdx.x;    // 0..511
  const int lane = t & 63;
  const int w = t >> 6;         // 0..7
  const int l31 = lane & 31, hi = lane >> 5;
  // T1 XCD-chunked swizzle (256 blocks, 32 per XCD chunk)
  const int id = blockIdx.y * 4 + blockIdx.x;
  const int work = (id & 7) * 32 + (id >> 3);
  const int bx = work & 3;
  const int bh = work >> 2;
  const int b = bh >> 5, h = bh & 31;
  const int kvh = h >> 2;  // G = 4

  const u16* Qbase = Q + ((size_t)(b * 32 + h) * 2048) * 64;
  const u16* Kbase = Kg + ((size_t)(b * 8 + kvh) * 2048) * 64;
  const u16* Vbase = Vg + ((size_t)(b * 8 + kvh) * 64) * 2048;

  // staging precompute: thread covers 2 K-chunks + 2 V-chunks per tile
  int kro[2], kco[2], vro[2], vco[2];
#pragma unroll
  for (int p = 0; p < 2; ++p) {
    int c = t + p * 512;
    kro[p] = c >> 3;
    kco[p] = ((c & 7) ^ (kro[p] & 7)) * 8;
    vro[p] = c >> 4;
    vco[p] = ((c & 15) ^ (vro[p] & 15)) * 8;
  }

  // read-side swizzled chunk offsets
  int off8[4];   // K: chunk 2dc+hi of 8, rows%8-swizzled
#pragma unroll
  for (int c = 0; c < 4; ++c) off8[c] = ((2 * c + hi) ^ (l31 & 7)) * 8;
  int off16[8];  // V: chunk 2kk+hi of 16, rows%16-swizzled
#pragma unroll
  for (int c = 0; c < 8; ++c) off16[c] = ((2 * c + hi) ^ (l31 & 15)) * 8;
  const int rbB = l31 * 64;

  for (int ph = 0; ph < 2; ++ph) {
    const int qt = ph ? 7 - bx : bx;
    const int q0 = qt * 256;
    const int rbase = q0 + w * 32;
    const int qrow = rbase + l31;  // this lane's q-row (S^T column)

    s16x8 qf[4];
#pragma unroll
    for (int dc = 0; dc < 4; ++dc)
      qf[dc] = ld8(Qbase + (size_t)qrow * 64 + dc * 16 + hi * 8);

    f32x16 oacc[2];
#pragma unroll
    for (int dn = 0; dn < 2; ++dn)
#pragma unroll
      for (int r = 0; r < 16; ++r) oacc[dn][r] = 0.f;
    float lacc = 0.f;

    const int nkt = 2 * qt + 2;  // 128-key tiles covering q0+256 rows

    __syncthreads();  // previous phase's LDS reads done before restaging buf0
#pragma unroll
    for (int p = 0; p < 2; ++p) {
      async16(Kbase + (size_t)kro[p] * 64 + kco[p], &Ks[0][(t + p * 512) * 8]);
      async16(Vbase + (size_t)vro[p] * 2048 + vco[p],
              &Vs[0][(t + p * 512) * 8]);
    }

    for (int kt = 0; kt < nkt; ++kt) {
      const int cur = kt & 1;
      __syncthreads();  // buf[cur] staged; prev reads of buf[1-cur] done
      if (kt + 1 < nkt) {
        const int nxt = 1 - cur;
        const u16* kg = Kbase + (size_t)(kt + 1) * 8192;
        const u16* vg = Vbase + (kt + 1) * 128;
#pragma unroll
        for (int p = 0; p < 2; ++p) {
          async16(kg + (size_t)kro[p] * 64 + kco[p],
                  &Ks[nxt][(t + p * 512) * 8]);
          async16(vg + (size_t)vro[p] * 2048 + vco[p],
                  &Vs[nxt][(t + p * 512) * 8]);
        }
      }
      const u16* Kb = Ks[cur];
      const u16* Vb = Vs[cur];

#pragma unroll
      for (int bs = 0; bs < 2; ++bs) {
        const int kb0 = kt * 128 + bs * 64;
        if (kb0 > rbase + 31) continue;  // fully-masked 64-key batch
        const bool dob = (kb0 + 32 <= rbase + 31);
        // --- both QK^T chains issued back-to-back (independent accs) ---
        f32x16 s0, s1;
#pragma unroll
        for (int r = 0; r < 16; ++r) s0[r] = 0.f;
#pragma unroll
        for (int r = 0; r < 16; ++r) s1[r] = 0.f;
        __builtin_amdgcn_s_setprio(1);
#pragma unroll
        for (int dc = 0; dc < 4; ++dc) {
          s16x8 kf = ld8(&Kb[(2 * bs) * 2048 + rbB + off8[dc]]);
          s0 = MFMA32(kf, qf[dc], s0);
        }
        if (dob) {
#pragma unroll
          for (int dc = 0; dc < 4; ++dc) {
            s16x8 kf = ld8(&Kb[(2 * bs + 1) * 2048 + rbB + off8[dc]]);
            s1 = MFMA32(kf, qf[dc], s1);
          }
        }
        __builtin_amdgcn_s_setprio(0);
        // --- causal masks (diagonal tiles only; wave-uniform branches) ---
        if (kb0 + 31 > rbase) {
          const int kb = kb0 + 4 * hi;
#pragma unroll
          for (int r = 0; r < 16; ++r)
            if (kb + (r & 3) + 8 * (r >> 2) > qrow) s0[r] = -1e30f;
        }
        if (dob && kb0 + 63 > rbase) {
          const int kb = kb0 + 32 + 4 * hi;
#pragma unroll
          for (int r = 0; r < 16; ++r)
            if (kb + (r & 3) + 8 * (r >> 2) > qrow) s1[r] = -1e30f;
        }
        // --- independent exp2 ---
        float p0[16], p1[16];
#pragma unroll
        for (int r = 0; r < 16; ++r) p0[r] = __builtin_amdgcn_exp2f(s0[r]);
        if (dob) {
#pragma unroll
          for (int r = 0; r < 16; ++r) p1[r] = __builtin_amdgcn_exp2f(s1[r]);
        }
        // --- l accumulation (balanced trees) ---
        {
          float e0 = p0[0] + p0[1], e1 = p0[2] + p0[3], e2 = p0[4] + p0[5],
                e3 = p0[6] + p0[7], e4 = p0[8] + p0[9], e5 = p0[10] + p0[11],
                e6 = p0[12] + p0[13], e7 = p0[14] + p0[15];
          lacc += ((e0 + e1) + (e2 + e3)) + ((e4 + e5) + (e6 + e7));
        }
        if (dob) {
          float e0 = p1[0] + p1[1], e1 = p1[2] + p1[3], e2 = p1[4] + p1[5],
                e3 = p1[6] + p1[7], e4 = p1[8] + p1[9], e5 = p1[10] + p1[11],
                e6 = p1[12] + p1[13], e7 = p1[14] + p1[15];
          lacc += ((e0 + e1) + (e2 + e3)) + ((e4 + e5) + (e6 + e7));
        }
        // --- T12 fragment builds for all live kk ---
        s16x8 F0, F1, F2, F3;
        {
          unsigned a0 = cvtpk(p0[0], p0[1]), b0 = cvtpk(p0[4], p0[5]);
          unsigned a1 = cvtpk(p0[2], p0[3]), b1 = cvtpk(p0[6], p0[7]);
          auto s0s = __builtin_amdgcn_permlane32_swap(a0, b0, false, false);
          auto s1s = __builtin_amdgcn_permlane32_swap(a1, b1, false, false);
          u32x4 fw = {(unsigned)s0s[0], (unsigned)s1s[0], (unsigned)s0s[1],
                      (unsigned)s1s[1]};
          F0 = __builtin_bit_cast(s16x8, fw);
          unsigned a2 = cvtpk(p0[8], p0[9]), b2 = cvtpk(p0[12], p0[13]);
          unsigned a3 = cvtpk(p0[10], p0[11]), b3 = cvtpk(p0[14], p0[15]);
          auto s2s = __builtin_amdgcn_permlane32_swap(a2, b2, false, false);
          auto s3s = __builtin_amdgcn_permlane32_swap(a3, b3, false, false);
          u32x4 fw2 = {(unsigned)s2s[0], (unsigned)s3s[0], (unsigned)s2s[1],
                       (unsigned)s3s[1]};
          F1 = __builtin_bit_cast(s16x8, fw2);
        }
        if (dob) {
          unsigned a0 = cvtpk(p1[0], p1[1]), b0 = cvtpk(p1[4], p1[5]);
          unsigned a1 = cvtpk(p1[2], p1[3]), b1 = cvtpk(p1[6], p1[7]);
          auto s0s = __builtin_amdgcn_permlane32_swap(a0, b0, false, false);
          auto s1s = __builtin_amdgcn_permlane32_swap(a1, b1, false, false);
          u32x4 fw = {(unsigned)s0s[0], (unsigned)s1s[0], (unsigned)s0s[1],
                      (unsigned)s1s[1]};
          F2 = __builtin_bit_cast(s16x8, fw);
          unsigned a2 = cvtpk(p1[8], p1[9]), b2 = cvtpk(p1[12], p1[13]);
          unsigned a3 = cvtpk(p1[10], p1[11]), b3 = cvtpk(p1[14], p1[15]);
          auto s2s = __builtin_amdgcn_permlane32_swap(a2, b2, false, false);
          auto s3s = __builtin_amdgcn_permlane32_swap(a3, b3, false, false);
          u32x4 fw2 = {(unsigned)s2s[0], (unsigned)s3s[0], (unsigned)s2s[1],
                       (unsigned)s3s[1]};
          F3 = __builtin_bit_cast(s16x8, fw2);
        }
        // --- all PV MFMAs, alternating accumulators (dep distance 2) ---
        // V chunk for fragment kk of this batch: off16[4*bs + kk]
        __builtin_amdgcn_s_setprio(1);
#pragma unroll
        for (int dn = 0; dn < 2; ++dn) {
          s16x8 vf = ld8(&Vb[(dn * 32 + l31) * 128 + off16[4 * bs + 0]]);
          oacc[dn] = MFMA32(F0, vf, oacc[dn]);
        }
#pragma unroll
        for (int dn = 0; dn < 2; ++dn) {
          s16x8 vf = ld8(&Vb[(dn * 32 + l31) * 128 + off16[4 * bs + 1]]);
          oacc[dn] = MFMA32(F1, vf, oacc[dn]);
        }
        if (dob) {
#pragma unroll
          for (int dn = 0; dn < 2; ++dn) {
            s16x8 vf = ld8(&Vb[(dn * 32 + l31) * 128 + off16[4 * bs + 2]]);
            oacc[dn] = MFMA32(F2, vf, oacc[dn]);
          }
#pragma unroll
          for (int dn = 0; dn < 2; ++dn) {
            s16x8 vf = ld8(&Vb[(dn * 32 + l31) * 128 + off16[4 * bs + 3]]);
            oacc[dn] = MFMA32(F3, vf, oacc[dn]);
          }
        }
        __builtin_amdgcn_s_setprio(0);
      }
    }

    // epilogue: l split across hi halves -> one shfl_xor(32), broadcast 1/l
    // through wave-private LDS, scale + store O
    {
      float ltot = lacc + __shfl_xor(lacc, 32);
      if (lane < 32) Lred[w * 32 + l31] = 1.f / ltot;
      f32x4 lv[4];
#pragma unroll
      for (int g = 0; g < 4; ++g)
        lv[g] = *(const f32x4*)&Lred[w * 32 + 8 * g + 4 * hi];
#pragma unroll
      for (int dn = 0; dn < 2; ++dn)
#pragma unroll
        for (int g = 0; g < 4; ++g)
#pragma unroll
          for (int j = 0; j < 4; ++j) {
            int s = rbase + 8 * g + 4 * hi + j;
            O[((size_t)(b * 2048 + s)) * 2048 + h * 64 + dn * 32 + l31] =
                f2bf(oacc[dn][4 * g + j] * lv[g][j]);
          }
    }
  }
}

// ---------------- launch ----------------
extern "C" void kernel_launch(void* const* d_in, const int* in_sizes, int n_in,
                              void* d_out, int out_size, void* d_ws,
                              size_t ws_size, hipStream_t stream) {
  const float* X = (const float*)d_in[0];
  const float* cosp = (const float*)d_in[1];
  const float* sinp = (const float*)d_in[2];
  const float* Wq = (const float*)d_in[4];
  const float* Wk = (const float*)d_in[5];
  const float* Wv = (const float*)d_in[6];
  const float* Wo = (const float*)d_in[7];
  float* out = (float*)d_out;

  u16* Xb = (u16*)d_ws;       // 8,388,608
  u16* Wqkv = Xb + 8388608;   // 3072x2048 (Wq|Wk|Wv rows)
  u16* Wob = Wqkv + 6291456;  // 4,194,304
  u16* Qr = Wob + 4194304;    // [2][32][2048][64]  (pre-scaled)
  u16* Kr = Qr + 8388608;     // [2][8][2048][64]
  u16* Vt = Kr + 2097152;     // [2][8][64][2048]
  u16* Ob = Vt + 2097152;     // [2][2048][2048]

  cvt_all<<<18432, 256, 0, stream>>>(X, Wq, Wk, Wv, Wo, Xb);

  gemm_nt<EPI_QKV><<<dim3(24, 32), 256, 0, stream>>>(
      Xb, Wqkv, cosp, sinp, Qr, Kr, Vt, nullptr, 2048);

  attn<<<dim3(4, 64), 512, 0, stream>>>(Qr, Kr, Vt, Ob);

  gemm_nt<EPI_OUT><<<dim3(16, 32), 256, 0, stream>>>(
      Ob, Wob, nullptr, nullptr, nullptr, nullptr, nullptr, out, 2048);
}